// Round 10
// baseline (406.701 us; speedup 1.0000x reference)
//
#include <hip/hip_runtime.h>

// DeltaNet fused pipeline, round 15 (= round 14 + LDS-free k_out):
//   k_cast:    x fp32 -> bf16
//   k_transw:  Wq/Wk/Wv -> Wt (N x K bf16), Wo -> Wot, Wg -> Wgt16 (z==4)
//   k_gemm:    bf16 MFMA 128x128 GEMM (QKV), plain block mapping (117us)
//   k_betaW:   wave-per-row dot: beta = clip(sigmoid(xb . Wgt16[h] + bg))
//   k_prep:    G-scan + RoPE + phi + intra-chunk A + V-pack + FUSED k_kv
//   k_sprefix: in-place weighted prefix over Mg/mzg, 4-deep pipelined
//   k_out:     REWRITTEN LDS-free: A-operand frags (Q,A rows) are per-wave
//              disjoint -> direct global->reg; B-operands (S,V) L2-resident
//              (74KB/block); denom reuses aq/aa register frags; per-row inv
//              via in-wave __shfl. 0 LDS, 0 barriers -> ~5 blocks/CU
//              (was 79KB LDS, 2/CU, 2 barriers).
//   k_gemm2:   256x128 triple-buffered GEMM (out-proj), round-12 swizzle
//
// workspace layout (134,742,016 B):
//   0         xb (16.8M) [dead after betaW] -> Qt (prep->out)
//   16777216  Wt (25.2M) [dead after QKV gemm] -> mzg(0.5M)+gch(4K)
//   33554432  Ag (8.4M)  (prep->out)
//   41943040  Wot (8.4M) (transw->final gemm)
//   50331648  qkvb (50.3M) (gemm->prep; dead after)
//   100663296 numerb (16.8M) (out->final gemm)
//   117440512 Vg (16.8M) (prep->out)
//   134217728 beta (0.26M), 134479872 Wgt16 (64K)
//   d_out     Mg/Sg bf16 33.5M (prep->sprefix->out; overwritten by final gemm)

typedef __attribute__((ext_vector_type(8))) short short8;
typedef __attribute__((ext_vector_type(4))) float f32x4;

__device__ __forceinline__ unsigned short f2bf(float f) {
  unsigned u = __float_as_uint(f);
  u += 0x7fffu + ((u >> 16) & 1u);   // RNE
  return (unsigned short)(u >> 16);
}
__device__ __forceinline__ float bf2f(unsigned short s) {
  return __uint_as_float(((unsigned)s) << 16);
}
__device__ __forceinline__ float phi_elu1(float x) {
  return x > 0.f ? x + 1.f : expf(x);
}
__device__ __forceinline__ void gl_lds16(const void* g, void* l) {
  __builtin_amdgcn_global_load_lds(
      (const __attribute__((address_space(1))) void*)g,
      (__attribute__((address_space(3))) void*)l, 16, 0, 0);
}
__device__ __forceinline__ void bar_raw() {
  asm volatile("" ::: "memory");
  __builtin_amdgcn_s_barrier();
  asm volatile("" ::: "memory");
}

// ---------------- cast x -> bf16 ----------------
__global__ __launch_bounds__(256)
void k_cast(const float* __restrict__ x, unsigned short* __restrict__ xb) {
  int i = (blockIdx.x * 256 + threadIdx.x) * 4;
  float4 f = *(const float4*)(x + i);
  uint2 p;
  p.x = (unsigned)f2bf(f.x) | ((unsigned)f2bf(f.y) << 16);
  p.y = (unsigned)f2bf(f.z) | ((unsigned)f2bf(f.w) << 16);
  *(uint2*)(xb + i) = p;
}

// ---------------- transpose+cast weights ----------------
__global__ __launch_bounds__(256)
void k_transw(const float* __restrict__ Wq, const float* __restrict__ Wk,
              const float* __restrict__ Wv, const float* __restrict__ Wo,
              const float* __restrict__ Wg,
              unsigned short* __restrict__ Wt, unsigned short* __restrict__ Wot,
              unsigned short* __restrict__ Wgt16) {
  const int z = blockIdx.z;
  if (z == 4) {
    if (blockIdx.y != 0) return;
    int idx = blockIdx.x * 256 + threadIdx.x;  // 8192 threads
    int h = idx >> 9, k4 = (idx & 511) * 4;
    uint2 p;
    p.x = (unsigned)f2bf(Wg[(k4 + 0) * 16 + h]) | ((unsigned)f2bf(Wg[(k4 + 1) * 16 + h]) << 16);
    p.y = (unsigned)f2bf(Wg[(k4 + 2) * 16 + h]) | ((unsigned)f2bf(Wg[(k4 + 3) * 16 + h]) << 16);
    *(uint2*)(Wgt16 + (size_t)h * 2048 + k4) = p;
    return;
  }
  const float* W = (z == 0) ? Wq : (z == 1) ? Wk : (z == 2) ? Wv : Wo;
  unsigned short* out = (z < 3) ? (Wt + (size_t)z * 2048 * 2048) : Wot;
  __shared__ float tile[64][65];
  const int n0 = blockIdx.x * 64;
  const int k0 = blockIdx.y * 64;
  const int tx = threadIdx.x & 63;
  const int ty = threadIdx.x >> 6;
#pragma unroll
  for (int rl = 0; rl < 16; ++rl) {
    int kk = rl * 4 + ty;
    tile[kk][tx] = W[(size_t)(k0 + kk) * 2048 + n0 + tx];
  }
  __syncthreads();
#pragma unroll
  for (int rl = 0; rl < 16; ++rl) {
    int nn = rl * 4 + ty;
    out[(size_t)(n0 + nn) * 2048 + k0 + tx] = f2bf(tile[tx][nn]);
  }
}

// ---------------- beta ----------------
__global__ __launch_bounds__(256)
void k_betaW(const unsigned short* __restrict__ xb, const unsigned short* __restrict__ Wgt16,
             const float* __restrict__ bg, float* __restrict__ beta) {
  const int w = threadIdx.x >> 6;
  const int lane = threadIdx.x & 63;
  const int m = blockIdx.x * 4 + w;
  const int h = lane & 15, kq = lane >> 4;
  const unsigned short* xr = xb + (size_t)m * 2048 + kq * 512;
  const unsigned short* wr = Wgt16 + (size_t)h * 2048 + kq * 512;
  float acc = 0.f;
#pragma unroll 8
  for (int i = 0; i < 64; ++i) {
    short8 xv = *(const short8*)(xr + i * 8);
    short8 wv = *(const short8*)(wr + i * 8);
#pragma unroll
    for (int j = 0; j < 8; ++j)
      acc = fmaf(bf2f((unsigned short)xv[j]), bf2f((unsigned short)wv[j]), acc);
  }
  acc += __shfl_xor(acc, 16, 64);
  acc += __shfl_xor(acc, 32, 64);
  if (lane < 16) {
    float v = acc + bg[h];
    float bv = 1.f / (1.f + expf(-v));
    beta[(size_t)m * 16 + h] = fminf(fmaxf(bv, 0.8f), 0.9995f);
  }
}

// ---------------- bf16 MFMA GEMM 128x128 (QKV), plain mapping ----------------
template <bool OUT_BF16, bool ADD_BIAS>
__global__ __launch_bounds__(256)
void k_gemm(const unsigned short* __restrict__ A, const unsigned short* __restrict__ Bt,
            void* __restrict__ Cptr, const float* __restrict__ bias,
            int M, int N, int K, int ldA, int ldC) {
  __shared__ __align__(16) unsigned short As[128][64];
  __shared__ __align__(16) unsigned short Bs[128][64];
  const int tid = threadIdx.x;
  const int n0 = blockIdx.x * 128;
  const int m0 = blockIdx.y * 128;
  const int lane = tid & 63;
  const int w = tid >> 6;
  const int wm = w >> 1, wn = w & 1;
  const int q = lane >> 4, r = lane & 15;

  const int srow0 = w * 8 + (lane >> 3);
  const int scol = ((lane & 7) ^ ((lane >> 3) & 7)) * 8;

  f32x4 acc[4][4];
#pragma unroll
  for (int i = 0; i < 4; ++i)
#pragma unroll
    for (int j = 0; j < 4; ++j) acc[i][j] = (f32x4){0.f, 0.f, 0.f, 0.f};

  const unsigned short* A0 = A + (size_t)(m0 + srow0) * ldA + scol;
  const unsigned short* B0 = Bt + (size_t)(n0 + srow0) * K + scol;
  unsigned short* lA = &As[srow0][(lane & 7) * 8];
  unsigned short* lB = &Bs[srow0][(lane & 7) * 8];

  const int rsw = r & 7;

  for (int kt = 0; kt < K; kt += 64) {
    __syncthreads();
#pragma unroll
    for (int i = 0; i < 4; ++i) {
      gl_lds16(A0 + (size_t)i * 32 * ldA + kt, lA + i * 2048);
      gl_lds16(B0 + (size_t)i * 32 * K + kt, lB + i * 2048);
    }
    __syncthreads();
#pragma unroll
    for (int kk = 0; kk < 2; ++kk) {
      const int ps = ((kk * 4 + q) ^ rsw) * 8;
      short8 af[4], bfr[4];
#pragma unroll
      for (int i = 0; i < 4; ++i)
        af[i] = *(const short8*)&As[wm * 64 + i * 16 + r][ps];
#pragma unroll
      for (int j = 0; j < 4; ++j)
        bfr[j] = *(const short8*)&Bs[wn * 64 + j * 16 + r][ps];
#pragma unroll
      for (int i = 0; i < 4; ++i)
#pragma unroll
        for (int j = 0; j < 4; ++j)
          acc[i][j] = __builtin_amdgcn_mfma_f32_16x16x32_bf16(af[i], bfr[j], acc[i][j], 0, 0, 0);
    }
  }
#pragma unroll
  for (int i = 0; i < 4; ++i) {
#pragma unroll
    for (int j = 0; j < 4; ++j) {
#pragma unroll
      for (int rr = 0; rr < 4; ++rr) {
        int mi = m0 + wm * 64 + i * 16 + q * 4 + rr;
        int ni = n0 + wn * 64 + j * 16 + r;
        float val = acc[i][j][rr];
        if (ADD_BIAS) val += bias[ni];
        if (OUT_BF16)
          ((unsigned short*)Cptr)[(size_t)mi * ldC + ni] = f2bf(val);
        else
          ((float*)Cptr)[(size_t)mi * ldC + ni] = val;
      }
    }
  }
}

// ---------------- bf16 MFMA GEMM 256x128, triple-buffered (out-proj) ----------------
template <bool OUT_BF16, bool ADD_BIAS>
__global__ __launch_bounds__(512, 2)
void k_gemm2(const unsigned short* __restrict__ A, const unsigned short* __restrict__ Bt,
             void* __restrict__ Cptr, const float* __restrict__ bias,
             int M, int N, int K, int ldA, int ldC) {
  __shared__ __align__(16) unsigned short Ls[3][3][128][64];  // 144KB
  const int tid = threadIdx.x;
  const int lane = tid & 63;
  const int w = tid >> 6;
  const int wm = w >> 1;
  const int wn = w & 1;
  const int ql = lane >> 4;
  const int r = lane & 15;

  // round-12 swizzle (proven in the 407us pipeline)
  const int nwg = gridDim.x * gridDim.y;
  const int orig = blockIdx.y * gridDim.x + blockIdx.x;
  const int li = (orig & 7) * (nwg >> 3) + (orig >> 3);
  const int m0 = (li & 15) * 256;
  const int n0 = (li >> 4) * 128;

  const int srow = tid >> 3;
  const int sphys = tid & 7;
  const int slog = sphys ^ (srow & 7);
  const unsigned short* Ab = A + (size_t)(m0 + srow) * ldA + slog * 8;
  const unsigned short* Bb = Bt + (size_t)(n0 + srow) * K + slog * 8;

#define STG(st, h, tt)                                                        \
  do {                                                                        \
    const size_t ldx = ((h) == 2) ? (size_t)K : (size_t)ldA;                  \
    const unsigned short* gs =                                                \
        (((h) == 2) ? Bb : (Ab + (size_t)((h) * 128) * ldA)) +                \
        (size_t)(tt) * 64;                                                    \
    unsigned short* ld = &Ls[(st)][(h)][srow][sphys * 8];                     \
    gl_lds16(gs, ld);                                                         \
    gl_lds16(gs + 64 * ldx, ld + 64 * 64);                                    \
  } while (0)

  f32x4 acc[4][4];
#pragma unroll
  for (int i = 0; i < 4; ++i)
#pragma unroll
    for (int j = 0; j < 4; ++j) acc[i][j] = (f32x4){0.f, 0.f, 0.f, 0.f};

  const int NT = K >> 6;

#pragma unroll
  for (int h = 0; h < 3; ++h) STG(0, h, 0);
#pragma unroll
  for (int h = 0; h < 3; ++h) STG(1, h, 1);
  asm volatile("s_waitcnt vmcnt(6)" ::: "memory");
  bar_raw();

  short8 bfr[4][2];

  for (int t = 0; t < NT; ++t) {
    const int st = t % 3;
    const unsigned short (*LA)[64] = Ls[st][wm >> 1];
    const unsigned short (*LB)[64] = Ls[st][2];
    const int arow0 = (wm & 1) * 64;
    const int brow0 = wn * 64;
    const bool pf = (t + 2 < NT);
    const int s2 = (t + 2) % 3;
#pragma unroll
    for (int p = 0; p < 2; ++p) {
      if (p == 0) {
#pragma unroll
        for (int nj = 0; nj < 4; ++nj)
#pragma unroll
          for (int kk = 0; kk < 2; ++kk)
            bfr[nj][kk] = *(const short8*)
                &LB[brow0 + nj * 16 + r][((kk * 4 + ql) ^ (r & 7)) * 8];
      }
      short8 af[2][2];
#pragma unroll
      for (int im = 0; im < 2; ++im)
#pragma unroll
        for (int kk = 0; kk < 2; ++kk)
          af[im][kk] = *(const short8*)
              &LA[arow0 + (p * 2 + im) * 16 + r][((kk * 4 + ql) ^ (r & 7)) * 8];
      if (pf) {
        if (p == 0) {
          STG(s2, 0, t + 2);
          STG(s2, 1, t + 2);
        } else {
          STG(s2, 2, t + 2);
        }
      }
      bar_raw();
      __builtin_amdgcn_s_setprio(1);
#pragma unroll
      for (int kk = 0; kk < 2; ++kk)
#pragma unroll
        for (int im = 0; im < 2; ++im)
#pragma unroll
          for (int nj = 0; nj < 4; ++nj)
            acc[p * 2 + im][nj] = __builtin_amdgcn_mfma_f32_16x16x32_bf16(
                af[im][kk], bfr[nj][kk], acc[p * 2 + im][nj], 0, 0, 0);
      __builtin_amdgcn_s_setprio(0);
      if (p == 1) {
        if (pf)
          asm volatile("s_waitcnt vmcnt(6)" ::: "memory");
        else if (t + 1 < NT)
          asm volatile("s_waitcnt vmcnt(0)" ::: "memory");
      }
      __builtin_amdgcn_sched_barrier(0);
      bar_raw();
    }
  }
#undef STG

#pragma unroll
  for (int mi = 0; mi < 4; ++mi) {
#pragma unroll
    for (int nj = 0; nj < 4; ++nj) {
#pragma unroll
      for (int rr = 0; rr < 4; ++rr) {
        int mrow = m0 + wm * 64 + mi * 16 + ql * 4 + rr;
        int ncol = n0 + wn * 64 + nj * 16 + r;
        float val = acc[mi][nj][rr];
        if (ADD_BIAS) val += bias[ncol];
        if (OUT_BF16)
          ((unsigned short*)Cptr)[(size_t)mrow * ldC + ncol] = f2bf(val);
        else
          ((float*)Cptr)[(size_t)mrow * ldC + ncol] = val;
      }
    }
  }
}

// ---------------- prep: G-scan + RoPE + phi + A + V-pack + FUSED kv ----------------
__global__ __launch_bounds__(256)
void k_prep(const unsigned short* __restrict__ qkv, const float* __restrict__ beta,
            unsigned short* __restrict__ Qt, unsigned short* __restrict__ Ag,
            unsigned short* __restrict__ Vg, unsigned short* __restrict__ Mg,
            float* __restrict__ mzg, float* __restrict__ gch) {
  const int ch = blockIdx.x;
  const int bh = blockIdx.y;
  const int b = bh >> 4, h = bh & 15;
  const int tid = threadIdx.x;
  const int t0 = ch * 64;

  __shared__ float Gs[64];
  __shared__ unsigned short Qs[64][132];   // 16.9KB
  __shared__ unsigned short Ks[64][132];   // 16.9KB
  __shared__ unsigned short Vs[128][72];   // 18.4KB  [e][s]
  __shared__ unsigned short Kts[128][72];  // 18.4KB  [d][s]  (total ~71KB -> 2/CU)

  if (tid < 64) {
    float bb = beta[((size_t)(b * 2048 + t0 + tid)) * 16 + h];
#pragma unroll
    for (int off = 1; off < 64; off <<= 1) {
      float o = __shfl_up(bb, off, 64);
      if (tid >= off) bb *= o;
    }
    Gs[tid] = bb;
    if (tid == 63) gch[bh * 32 + ch] = bb;
  }
  __syncthreads();

  const int dgl = tid & 7;
  float invf[8];
#pragma unroll
  for (int j = 0; j < 8; ++j)
    invf[j] = expf((float)(dgl * 8 + j) * -0.14391156831212787f);  // 10000^(-e/64)

  int s = tid >> 3;
#pragma unroll
  for (int rep = 0; rep < 2; ++rep, s += 32) {
    size_t row = ((size_t)(b * 2048 + t0 + s)) * 6144 + (size_t)h * 128;
    short8 qlo = *(const short8*)(qkv + row + dgl * 8);
    short8 qhi = *(const short8*)(qkv + row + 64 + dgl * 8);
    short8 klo = *(const short8*)(qkv + row + 2048 + dgl * 8);
    short8 khi = *(const short8*)(qkv + row + 2048 + 64 + dgl * 8);
    float g = Gs[s];
    float ig = 1.f / g;
    float tg = (float)(t0 + s);
    short8 oql, oqh, okl, okh;
#pragma unroll
    for (int j = 0; j < 8; ++j) {
      float sn, cs;
      __sincosf(tg * invf[j], &sn, &cs);
      float qe = bf2f((unsigned short)qlo[j]), qo = bf2f((unsigned short)qhi[j]);
      float a0 = qe * cs - qo * sn, a1 = qe * sn + qo * cs;
      oql[j] = (short)f2bf(phi_elu1(a0) * g);
      oqh[j] = (short)f2bf(phi_elu1(a1) * g);
      float ke = bf2f((unsigned short)klo[j]), ko = bf2f((unsigned short)khi[j]);
      a0 = ke * cs - ko * sn;
      a1 = ke * sn + ko * cs;
      okl[j] = (short)f2bf(phi_elu1(a0) * ig);
      okh[j] = (short)f2bf(phi_elu1(a1) * ig);
    }
    size_t qbase = (((size_t)bh * 32 + ch) * 64 + s) * 128;
    *(short8*)(Qt + qbase + dgl * 8) = oql;
    *(short8*)(Qt + qbase + 64 + dgl * 8) = oqh;
    *(short8*)&Qs[s][dgl * 8] = oql;
    *(short8*)&Qs[s][64 + dgl * 8] = oqh;
    *(short8*)&Ks[s][dgl * 8] = okl;
    *(short8*)&Ks[s][64 + dgl * 8] = okh;
  }
  // V transpose scatter: thread handles row s2, 32 e-values
  {
    const int s2 = tid >> 2, qe = tid & 3;
    const unsigned short* vrow =
        qkv + ((size_t)(b * 2048 + t0 + s2)) * 6144 + 4096 + (size_t)h * 128 + qe * 32;
#pragma unroll
    for (int i = 0; i < 4; ++i) {
      short8 vv = *(const short8*)(vrow + i * 8);
#pragma unroll
      for (int j = 0; j < 8; ++j) Vs[qe * 32 + i * 8 + j][s2] = (unsigned short)vv[j];
    }
  }
  __syncthreads();

  // Kt pack: thread (d, sh) builds Kt[d][sh*32..+31] -> LDS Kts + mz + Vg out
  {
    const int d = tid >> 1, sh = tid & 1;
    unsigned pk[16];
#pragma unroll
    for (int i = 0; i < 16; ++i)
      pk[i] = (unsigned)Ks[sh * 32 + 2 * i][d] | ((unsigned)Ks[sh * 32 + 2 * i + 1][d] << 16);
#pragma unroll
    for (int i = 0; i < 4; ++i)
      *(uint4*)&Kts[d][sh * 32 + i * 8] = *(uint4*)&pk[i * 4];
    // mz[d] = rowsum_s Kt[d][s] directly from registers
    float zs = 0.f;
#pragma unroll
    for (int i = 0; i < 16; ++i) {
      zs += bf2f((unsigned short)(pk[i] & 0xffffu));
      zs += bf2f((unsigned short)(pk[i] >> 16));
    }
    zs += __shfl_xor(zs, 1, 64);
    if (sh == 0) mzg[((size_t)bh * 32 + ch) * 128 + d] = zs;
    // Vg write: [e][s] packed
    unsigned short* vr = Vg + ((size_t)bh * 32 + ch) * 8192 + (size_t)d * 64 + sh * 32;
#pragma unroll
    for (int i = 0; i < 4; ++i)
      *(uint4*)(vr + i * 8) = *(const uint4*)&Vs[d][sh * 32 + i * 8];
  }

  // intra-chunk A (reads Qs/Ks only)
  {
    const int lane = tid & 63;
    const int w = tid >> 6;
    const int q = lane >> 4, r = lane & 15;
    f32x4 acc[4];
#pragma unroll
    for (int nt = 0; nt < 4; ++nt) acc[nt] = (f32x4){0.f, 0.f, 0.f, 0.f};
#pragma unroll
    for (int kk = 0; kk < 4; ++kk) {
      short8 af = *(const short8*)&Qs[w * 16 + r][kk * 32 + q * 8];
#pragma unroll
      for (int nt = 0; nt < 4; ++nt) {
        short8 bf = *(const short8*)&Ks[nt * 16 + r][kk * 32 + q * 8];
        acc[nt] = __builtin_amdgcn_mfma_f32_16x16x32_bf16(af, bf, acc[nt], 0, 0, 0);
      }
    }
    unsigned short* Agp = Ag + ((size_t)bh * 32 + ch) * 4096;
#pragma unroll
    for (int nt = 0; nt < 4; ++nt) {
#pragma unroll
      for (int rr = 0; rr < 4; ++rr) {
        int t_l = w * 16 + q * 4 + rr;
        int s_l = nt * 16 + r;
        float val = (s_l <= t_l) ? acc[nt][rr] : 0.f;
        Agp[t_l * 64 + s_l] = f2bf(val);
      }
    }
  }

  __syncthreads();  // Kts ready

  // fused k_kv: M[e][d] = sum_s V[e][s] Kt[d][s]
  {
    const int lane = tid & 63;
    const int w = tid >> 6;
    const int q = lane >> 4, r = lane & 15;
    f32x4 acc[2][8];
#pragma unroll
    for (int jj = 0; jj < 2; ++jj)
#pragma unroll
      for (int i = 0; i < 8; ++i) acc[jj][i] = (f32x4){0.f, 0.f, 0.f, 0.f};
#pragma unroll
    for (int kk = 0; kk < 2; ++kk) {
      short8 af[2];
      af[0] = *(const short8*)&Vs[(w * 2 + 0) * 16 + r][kk * 32 + q * 8];
      af[1] = *(const short8*)&Vs[(w * 2 + 1) * 16 + r][kk * 32 + q * 8];
#pragma unroll
      for (int i = 0; i < 8; ++i) {
        short8 bf = *(const short8*)&Kts[i * 16 + r][kk * 32 + q * 8];
        acc[0][i] = __builtin_amdgcn_mfma_f32_16x16x32_bf16(af[0], bf, acc[0][i], 0, 0, 0);
        acc[1][i] = __builtin_amdgcn_mfma_f32_16x16x32_bf16(af[1], bf, acc[1][i], 0, 0, 0);
      }
    }
    unsigned short* Mp = Mg + ((size_t)bh * 32 + ch) * 16384;
#pragma unroll
    for (int jj = 0; jj < 2; ++jj)
#pragma unroll
      for (int i = 0; i < 8; ++i)
#pragma unroll
        for (int rr = 0; rr < 4; ++rr) {
          int e = (w * 2 + jj) * 16 + q * 4 + rr;
          Mp[e * 128 + i * 16 + r] = f2bf(acc[jj][i][rr]);
        }
  }
}

// ---------------- k_sprefix: in-place weighted prefix, 4-deep pipelined -------
__global__ __launch_bounds__(256)
void k_sprefix(unsigned short* __restrict__ Msg, float* __restrict__ mzg,
               const float* __restrict__ gch) {
  const int es = blockIdx.x;
  const int bh = blockIdx.y;
  const int tid = threadIdx.x;
  const int e = es * 16 + (tid >> 4);
  const int d0 = (tid & 15) * 8;
  unsigned short* base = Msg + (size_t)bh * 32 * 16384 + (size_t)e * 128 + d0;
  const float* gp = gch + bh * 32;
  float sv[8];
#pragma unroll
  for (int i = 0; i < 8; ++i) sv[i] = 0.f;
  uint4 mb[2][4];
#pragma unroll
  for (int i = 0; i < 4; ++i) mb[0][i] = *(const uint4*)(base + (size_t)i * 16384);
#pragma unroll
  for (int g = 0; g < 8; ++g) {
    if (g < 7) {
#pragma unroll
      for (int i = 0; i < 4; ++i)
        mb[(g + 1) & 1][i] = *(const uint4*)(base + (size_t)(4 * (g + 1) + i) * 16384);
    }
#pragma unroll
    for (int i = 0; i < 4; ++i) {
      const int c = 4 * g + i;
      uint4 so;
      so.x = (unsigned)f2bf(sv[0]) | ((unsigned)f2bf(sv[1]) << 16);
      so.y = (unsigned)f2bf(sv[2]) | ((unsigned)f2bf(sv[3]) << 16);
      so.z = (unsigned)f2bf(sv[4]) | ((unsigned)f2bf(sv[5]) << 16);
      so.w = (unsigned)f2bf(sv[6]) | ((unsigned)f2bf(sv[7]) << 16);
      *(uint4*)(base + (size_t)c * 16384) = so;
      float gv = gp[c];
      const unsigned short* mp = (const unsigned short*)&mb[g & 1][i];
#pragma unroll
      for (int j = 0; j < 8; ++j) sv[j] = gv * (sv[j] + bf2f(mp[j]));
    }
  }
  // z-prefix (once per bh), same 4-deep grouping
  if (es == 0 && tid < 128) {
    float* zb = mzg + (size_t)bh * 32 * 128 + tid;
    float z = 0.f;
    float zv[2][4];
#pragma unroll
    for (int i = 0; i < 4; ++i) zv[0][i] = zb[(size_t)i * 128];
#pragma unroll
    for (int g = 0; g < 8; ++g) {
      if (g < 7) {
#pragma unroll
        for (int i = 0; i < 4; ++i)
          zv[(g + 1) & 1][i] = zb[(size_t)(4 * (g + 1) + i) * 128];
      }
#pragma unroll
      for (int i = 0; i < 4; ++i) {
        const int c = 4 * g + i;
        zb[(size_t)c * 128] = z;
        z = gp[c] * (z + zv[g & 1][i]);
      }
    }
  }
}

// ---------------- k_out: LDS-free numer = Q@S + A@V; denom = rowsum(A)+Q.z ----
// A-operand frags (rows w*16+r of Q and A) are per-wave disjoint -> direct
// global->reg loads, reused for the denominator. B-operands (S [e][d],
// V [e][s]) read direct (L2-resident, 74KB/block, intra-block redundancy
// absorbed by L2). Per-row inverse broadcast via in-wave __shfl (each wave
// owns output rows w*16..w*16+15). No LDS, no barriers.
__global__ __launch_bounds__(256)
void k_out(const unsigned short* __restrict__ Qt, const unsigned short* __restrict__ Sg,
           const unsigned short* __restrict__ Ag, const unsigned short* __restrict__ Vg,
           const float* __restrict__ zg, unsigned short* __restrict__ numerb) {
  const int ch = blockIdx.x, bh = blockIdx.y;
  const int b = bh >> 4, h = bh & 15;
  const int tid = threadIdx.x, lane = tid & 63, w = tid >> 6;
  const int q = lane >> 4, r = lane & 15;

  const unsigned short* Qg = Qt + ((size_t)bh * 32 + ch) * 8192 + (size_t)(w * 16 + r) * 128;
  const unsigned short* Sp = Sg + ((size_t)bh * 32 + ch) * 16384;
  const unsigned short* Agp = Ag + ((size_t)bh * 32 + ch) * 4096 + (size_t)(w * 16 + r) * 64;
  const unsigned short* Vp = Vg + ((size_t)bh * 32 + ch) * 8192;
  const float* zp = zg + ((size_t)bh * 32 + ch) * 128;

  // A-operand fragments for this wave's 16 output rows (reused by denom)
  short8 aq[4], aa[2];
#pragma unroll
  for (int kk = 0; kk < 4; ++kk) aq[kk] = *(const short8*)(Qg + kk * 32 + q * 8);
#pragma unroll
  for (int kk = 0; kk < 2; ++kk) aa[kk] = *(const short8*)(Agp + kk * 32 + q * 8);

  f32x4 nacc[8];
#pragma unroll
  for (int j = 0; j < 8; ++j) nacc[j] = (f32x4){0.f, 0.f, 0.f, 0.f};
#pragma unroll
  for (int kk = 0; kk < 4; ++kk) {
#pragma unroll
    for (int j = 0; j < 8; ++j) {
      short8 bf = *(const short8*)(Sp + (size_t)(j * 16 + r) * 128 + kk * 32 + q * 8);
      nacc[j] = __builtin_amdgcn_mfma_f32_16x16x32_bf16(aq[kk], bf, nacc[j], 0, 0, 0);
    }
  }
#pragma unroll
  for (int kk = 0; kk < 2; ++kk) {
#pragma unroll
    for (int j = 0; j < 8; ++j) {
      short8 bf = *(const short8*)(Vp + (size_t)(j * 16 + r) * 64 + kk * 32 + q * 8);
      nacc[j] = __builtin_amdgcn_mfma_f32_16x16x32_bf16(aa[kk], bf, nacc[j], 0, 0, 0);
    }
  }

  // denom for row w*16+r from the register frags; z direct from global (L2)
  float dsum = 0.f;
#pragma unroll
  for (int kk = 0; kk < 4; ++kk) {
    float4 z0a = *(const float4*)(zp + kk * 32 + q * 8);
    float4 z0b = *(const float4*)(zp + kk * 32 + q * 8 + 4);
    dsum = fmaf(bf2f((unsigned short)aq[kk][0]), z0a.x, dsum);
    dsum = fmaf(bf2f((unsigned short)aq[kk][1]), z0a.y, dsum);
    dsum = fmaf(bf2f((unsigned short)aq[kk][2]), z0a.z, dsum);
    dsum = fmaf(bf2f((unsigned short)aq[kk][3]), z0a.w, dsum);
    dsum = fmaf(bf2f((unsigned short)aq[kk][4]), z0b.x, dsum);
    dsum = fmaf(bf2f((unsigned short)aq[kk][5]), z0b.y, dsum);
    dsum = fmaf(bf2f((unsigned short)aq[kk][6]), z0b.z, dsum);
    dsum = fmaf(bf2f((unsigned short)aq[kk][7]), z0b.w, dsum);
  }
#pragma unroll
  for (int kk = 0; kk < 2; ++kk)
#pragma unroll
    for (int j = 0; j < 8; ++j) dsum += bf2f((unsigned short)aa[kk][j]);
  dsum += __shfl_xor(dsum, 16, 64);
  dsum += __shfl_xor(dsum, 32, 64);
  const float inv = 1.f / (dsum + 1e-6f);

  // store: inv for row w*16 + q*4+rr lives at lane (q*4+rr) (r'=q*4+rr, q'=0)
#pragma unroll
  for (int j = 0; j < 8; ++j) {
#pragma unroll
    for (int rr = 0; rr < 4; ++rr) {
      float inv_r = __shfl(inv, q * 4 + rr, 64);
      int t_l = w * 16 + q * 4 + rr;
      size_t m = (size_t)b * 2048 + ch * 64 + t_l;
      numerb[m * 2048 + h * 128 + j * 16 + r] = f2bf(nacc[j][rr] * inv_r);
    }
  }
}

extern "C" void kernel_launch(void* const* d_in, const int* in_sizes, int n_in,
                              void* d_out, int out_size, void* d_ws, size_t ws_size,
                              hipStream_t stream) {
  const float* x  = (const float*)d_in[0];
  const float* Wq = (const float*)d_in[1];
  const float* Wk = (const float*)d_in[2];
  const float* Wv = (const float*)d_in[3];
  const float* Wg = (const float*)d_in[4];
  const float* bg = (const float*)d_in[5];
  const float* Wo = (const float*)d_in[6];
  const float* bo = (const float*)d_in[7];

  char* ws = (char*)d_ws;
  unsigned short* xb    = (unsigned short*)(ws);             // 16.8MB; -> Qt
  unsigned short* Qt    = (unsigned short*)(ws);
  unsigned short* Wt    = (unsigned short*)(ws + 16777216);  // 25.2MB; dead after QKV
  float*          mzg   = (float*)(ws + 16777216);           // 0.5MB (prep->sprefix->out)
  float*          gch   = (float*)(ws + 17301504);           // 4KB (prep->sprefix)
  unsigned short* Ag    = (unsigned short*)(ws + 33554432);  // 8.4MB
  unsigned short* Wot   = (unsigned short*)(ws + 41943040);  // 8.4MB
  unsigned short* qkvb  = (unsigned short*)(ws + 50331648);  // 50.3MB; dead after prep
  unsigned short* numerb= (unsigned short*)(ws + 100663296); // 16.8MB
  unsigned short* Vg    = (unsigned short*)(ws + 117440512); // 16.8MB
  float*          beta  = (float*)(ws + 134217728);          // 0.26MB
  unsigned short* Wgt16 = (unsigned short*)(ws + 134479872); // 64KB
  // Mg/Sg bf16 33.5MB lives in d_out (exact fit; overwritten by final GEMM).
  unsigned short* Mg    = (unsigned short*)d_out;

  k_cast<<<8192, 256, 0, stream>>>(x, xb);
  k_transw<<<dim3(32, 32, 5), 256, 0, stream>>>(Wq, Wk, Wv, Wo, Wg, Wt, Wot, Wgt16);
  k_gemm<true, false><<<dim3(48, 32), 256, 0, stream>>>(
      xb, Wt, qkvb, nullptr, 4096, 6144, 2048, 2048, 6144);
  k_betaW<<<1024, 256, 0, stream>>>(xb, Wgt16, bg, beta);
  k_prep<<<dim3(32, 32), 256, 0, stream>>>(qkvb, beta, Qt, Ag, Vg, Mg, mzg, gch);
  k_sprefix<<<dim3(8, 32), 256, 0, stream>>>(Mg, mzg, gch);
  k_out<<<dim3(32, 32), 256, 0, stream>>>(Qt, Mg, Ag, Vg, mzg, numerb);
  k_gemm2<false, true><<<dim3(16, 16), 512, 0, stream>>>(
      numerb, Wot, d_out, bo, 4096, 2048, 2048, 2048, 2048);
}

// Round 11
// 403.559 us; speedup vs baseline: 1.0078x; 1.0078x over previous
//
#include <hip/hip_runtime.h>

// DeltaNet fused pipeline, round 16 (= round 14 [best, 395.6us] with the QKV
// GEMM split into two M-half dispatches for top-5 visibility of the hidden
// ~195us mid-pipeline; k_out's round-15 LDS-free variant REVERTED — it was
// +11us: 4x redundant uncoalesced S/V streaming beat the two barriers):
//   k_cast:    x fp32 -> bf16
//   k_transw:  Wq/Wk/Wv -> Wt (N x K bf16), Wo -> Wot, Wg -> Wgt16 (z==4)
//   k_gemm:    bf16 MFMA 128x128 GEMM (QKV), plain mapping, 2 dispatches of
//              M=2048 each (~58us) so mid-kernels surface in top-5
//   k_betaW:   wave-per-row dot: beta = clip(sigmoid(xb . Wgt16[h] + bg))
//   k_prep:    G-scan + RoPE + phi + intra-chunk A + V-pack + FUSED k_kv
//   k_sprefix: in-place weighted prefix over Mg/mzg, 4-deep pipelined
//   k_out:     round-14 LDS version (79KB LDS, 2/CU)
//   k_gemm2:   256x128 triple-buffered GEMM (out-proj), round-12 swizzle
//
// workspace layout (134,742,016 B):
//   0         xb (16.8M) [dead after betaW] -> Qt (prep->out)
//   16777216  Wt (25.2M) [dead after QKV gemm] -> mzg(0.5M)+gch(4K)
//   33554432  Ag (8.4M)  (prep->out)
//   41943040  Wot (8.4M) (transw->final gemm)
//   50331648  qkvb (50.3M) (gemm->prep; dead after)
//   100663296 numerb (16.8M) (out->final gemm)
//   117440512 Vg (16.8M) (prep->out)
//   134217728 beta (0.26M), 134479872 Wgt16 (64K)
//   d_out     Mg/Sg bf16 33.5M (prep->sprefix->out; overwritten by final gemm)

typedef __attribute__((ext_vector_type(8))) short short8;
typedef __attribute__((ext_vector_type(4))) float f32x4;

__device__ __forceinline__ unsigned short f2bf(float f) {
  unsigned u = __float_as_uint(f);
  u += 0x7fffu + ((u >> 16) & 1u);   // RNE
  return (unsigned short)(u >> 16);
}
__device__ __forceinline__ float bf2f(unsigned short s) {
  return __uint_as_float(((unsigned)s) << 16);
}
__device__ __forceinline__ float phi_elu1(float x) {
  return x > 0.f ? x + 1.f : expf(x);
}
__device__ __forceinline__ void gl_lds16(const void* g, void* l) {
  __builtin_amdgcn_global_load_lds(
      (const __attribute__((address_space(1))) void*)g,
      (__attribute__((address_space(3))) void*)l, 16, 0, 0);
}
__device__ __forceinline__ void bar_raw() {
  asm volatile("" ::: "memory");
  __builtin_amdgcn_s_barrier();
  asm volatile("" ::: "memory");
}

// ---------------- cast x -> bf16 ----------------
__global__ __launch_bounds__(256)
void k_cast(const float* __restrict__ x, unsigned short* __restrict__ xb) {
  int i = (blockIdx.x * 256 + threadIdx.x) * 4;
  float4 f = *(const float4*)(x + i);
  uint2 p;
  p.x = (unsigned)f2bf(f.x) | ((unsigned)f2bf(f.y) << 16);
  p.y = (unsigned)f2bf(f.z) | ((unsigned)f2bf(f.w) << 16);
  *(uint2*)(xb + i) = p;
}

// ---------------- transpose+cast weights ----------------
__global__ __launch_bounds__(256)
void k_transw(const float* __restrict__ Wq, const float* __restrict__ Wk,
              const float* __restrict__ Wv, const float* __restrict__ Wo,
              const float* __restrict__ Wg,
              unsigned short* __restrict__ Wt, unsigned short* __restrict__ Wot,
              unsigned short* __restrict__ Wgt16) {
  const int z = blockIdx.z;
  if (z == 4) {
    if (blockIdx.y != 0) return;
    int idx = blockIdx.x * 256 + threadIdx.x;  // 8192 threads
    int h = idx >> 9, k4 = (idx & 511) * 4;
    uint2 p;
    p.x = (unsigned)f2bf(Wg[(k4 + 0) * 16 + h]) | ((unsigned)f2bf(Wg[(k4 + 1) * 16 + h]) << 16);
    p.y = (unsigned)f2bf(Wg[(k4 + 2) * 16 + h]) | ((unsigned)f2bf(Wg[(k4 + 3) * 16 + h]) << 16);
    *(uint2*)(Wgt16 + (size_t)h * 2048 + k4) = p;
    return;
  }
  const float* W = (z == 0) ? Wq : (z == 1) ? Wk : (z == 2) ? Wv : Wo;
  unsigned short* out = (z < 3) ? (Wt + (size_t)z * 2048 * 2048) : Wot;
  __shared__ float tile[64][65];
  const int n0 = blockIdx.x * 64;
  const int k0 = blockIdx.y * 64;
  const int tx = threadIdx.x & 63;
  const int ty = threadIdx.x >> 6;
#pragma unroll
  for (int rl = 0; rl < 16; ++rl) {
    int kk = rl * 4 + ty;
    tile[kk][tx] = W[(size_t)(k0 + kk) * 2048 + n0 + tx];
  }
  __syncthreads();
#pragma unroll
  for (int rl = 0; rl < 16; ++rl) {
    int nn = rl * 4 + ty;
    out[(size_t)(n0 + nn) * 2048 + k0 + tx] = f2bf(tile[tx][nn]);
  }
}

// ---------------- beta ----------------
__global__ __launch_bounds__(256)
void k_betaW(const unsigned short* __restrict__ xb, const unsigned short* __restrict__ Wgt16,
             const float* __restrict__ bg, float* __restrict__ beta) {
  const int w = threadIdx.x >> 6;
  const int lane = threadIdx.x & 63;
  const int m = blockIdx.x * 4 + w;
  const int h = lane & 15, kq = lane >> 4;
  const unsigned short* xr = xb + (size_t)m * 2048 + kq * 512;
  const unsigned short* wr = Wgt16 + (size_t)h * 2048 + kq * 512;
  float acc = 0.f;
#pragma unroll 8
  for (int i = 0; i < 64; ++i) {
    short8 xv = *(const short8*)(xr + i * 8);
    short8 wv = *(const short8*)(wr + i * 8);
#pragma unroll
    for (int j = 0; j < 8; ++j)
      acc = fmaf(bf2f((unsigned short)xv[j]), bf2f((unsigned short)wv[j]), acc);
  }
  acc += __shfl_xor(acc, 16, 64);
  acc += __shfl_xor(acc, 32, 64);
  if (lane < 16) {
    float v = acc + bg[h];
    float bv = 1.f / (1.f + expf(-v));
    beta[(size_t)m * 16 + h] = fminf(fmaxf(bv, 0.8f), 0.9995f);
  }
}

// ---------------- bf16 MFMA GEMM 128x128 (QKV), plain mapping ----------------
template <bool OUT_BF16, bool ADD_BIAS>
__global__ __launch_bounds__(256)
void k_gemm(const unsigned short* __restrict__ A, const unsigned short* __restrict__ Bt,
            void* __restrict__ Cptr, const float* __restrict__ bias,
            int M, int N, int K, int ldA, int ldC) {
  __shared__ __align__(16) unsigned short As[128][64];
  __shared__ __align__(16) unsigned short Bs[128][64];
  const int tid = threadIdx.x;
  const int n0 = blockIdx.x * 128;
  const int m0 = blockIdx.y * 128;
  const int lane = tid & 63;
  const int w = tid >> 6;
  const int wm = w >> 1, wn = w & 1;
  const int q = lane >> 4, r = lane & 15;

  const int srow0 = w * 8 + (lane >> 3);
  const int scol = ((lane & 7) ^ ((lane >> 3) & 7)) * 8;

  f32x4 acc[4][4];
#pragma unroll
  for (int i = 0; i < 4; ++i)
#pragma unroll
    for (int j = 0; j < 4; ++j) acc[i][j] = (f32x4){0.f, 0.f, 0.f, 0.f};

  const unsigned short* A0 = A + (size_t)(m0 + srow0) * ldA + scol;
  const unsigned short* B0 = Bt + (size_t)(n0 + srow0) * K + scol;
  unsigned short* lA = &As[srow0][(lane & 7) * 8];
  unsigned short* lB = &Bs[srow0][(lane & 7) * 8];

  const int rsw = r & 7;

  for (int kt = 0; kt < K; kt += 64) {
    __syncthreads();
#pragma unroll
    for (int i = 0; i < 4; ++i) {
      gl_lds16(A0 + (size_t)i * 32 * ldA + kt, lA + i * 2048);
      gl_lds16(B0 + (size_t)i * 32 * K + kt, lB + i * 2048);
    }
    __syncthreads();
#pragma unroll
    for (int kk = 0; kk < 2; ++kk) {
      const int ps = ((kk * 4 + q) ^ rsw) * 8;
      short8 af[4], bfr[4];
#pragma unroll
      for (int i = 0; i < 4; ++i)
        af[i] = *(const short8*)&As[wm * 64 + i * 16 + r][ps];
#pragma unroll
      for (int j = 0; j < 4; ++j)
        bfr[j] = *(const short8*)&Bs[wn * 64 + j * 16 + r][ps];
#pragma unroll
      for (int i = 0; i < 4; ++i)
#pragma unroll
        for (int j = 0; j < 4; ++j)
          acc[i][j] = __builtin_amdgcn_mfma_f32_16x16x32_bf16(af[i], bfr[j], acc[i][j], 0, 0, 0);
    }
  }
#pragma unroll
  for (int i = 0; i < 4; ++i) {
#pragma unroll
    for (int j = 0; j < 4; ++j) {
#pragma unroll
      for (int rr = 0; rr < 4; ++rr) {
        int mi = m0 + wm * 64 + i * 16 + q * 4 + rr;
        int ni = n0 + wn * 64 + j * 16 + r;
        float val = acc[i][j][rr];
        if (ADD_BIAS) val += bias[ni];
        if (OUT_BF16)
          ((unsigned short*)Cptr)[(size_t)mi * ldC + ni] = f2bf(val);
        else
          ((float*)Cptr)[(size_t)mi * ldC + ni] = val;
      }
    }
  }
}

// ---------------- bf16 MFMA GEMM 256x128, triple-buffered (out-proj) ----------------
template <bool OUT_BF16, bool ADD_BIAS>
__global__ __launch_bounds__(512, 2)
void k_gemm2(const unsigned short* __restrict__ A, const unsigned short* __restrict__ Bt,
             void* __restrict__ Cptr, const float* __restrict__ bias,
             int M, int N, int K, int ldA, int ldC) {
  __shared__ __align__(16) unsigned short Ls[3][3][128][64];  // 144KB
  const int tid = threadIdx.x;
  const int lane = tid & 63;
  const int w = tid >> 6;
  const int wm = w >> 1;
  const int wn = w & 1;
  const int ql = lane >> 4;
  const int r = lane & 15;

  // round-12 swizzle (proven in the 407us pipeline)
  const int nwg = gridDim.x * gridDim.y;
  const int orig = blockIdx.y * gridDim.x + blockIdx.x;
  const int li = (orig & 7) * (nwg >> 3) + (orig >> 3);
  const int m0 = (li & 15) * 256;
  const int n0 = (li >> 4) * 128;

  const int srow = tid >> 3;
  const int sphys = tid & 7;
  const int slog = sphys ^ (srow & 7);
  const unsigned short* Ab = A + (size_t)(m0 + srow) * ldA + slog * 8;
  const unsigned short* Bb = Bt + (size_t)(n0 + srow) * K + slog * 8;

#define STG(st, h, tt)                                                        \
  do {                                                                        \
    const size_t ldx = ((h) == 2) ? (size_t)K : (size_t)ldA;                  \
    const unsigned short* gs =                                                \
        (((h) == 2) ? Bb : (Ab + (size_t)((h) * 128) * ldA)) +                \
        (size_t)(tt) * 64;                                                    \
    unsigned short* ld = &Ls[(st)][(h)][srow][sphys * 8];                     \
    gl_lds16(gs, ld);                                                         \
    gl_lds16(gs + 64 * ldx, ld + 64 * 64);                                    \
  } while (0)

  f32x4 acc[4][4];
#pragma unroll
  for (int i = 0; i < 4; ++i)
#pragma unroll
    for (int j = 0; j < 4; ++j) acc[i][j] = (f32x4){0.f, 0.f, 0.f, 0.f};

  const int NT = K >> 6;

#pragma unroll
  for (int h = 0; h < 3; ++h) STG(0, h, 0);
#pragma unroll
  for (int h = 0; h < 3; ++h) STG(1, h, 1);
  asm volatile("s_waitcnt vmcnt(6)" ::: "memory");
  bar_raw();

  short8 bfr[4][2];

  for (int t = 0; t < NT; ++t) {
    const int st = t % 3;
    const unsigned short (*LA)[64] = Ls[st][wm >> 1];
    const unsigned short (*LB)[64] = Ls[st][2];
    const int arow0 = (wm & 1) * 64;
    const int brow0 = wn * 64;
    const bool pf = (t + 2 < NT);
    const int s2 = (t + 2) % 3;
#pragma unroll
    for (int p = 0; p < 2; ++p) {
      if (p == 0) {
#pragma unroll
        for (int nj = 0; nj < 4; ++nj)
#pragma unroll
          for (int kk = 0; kk < 2; ++kk)
            bfr[nj][kk] = *(const short8*)
                &LB[brow0 + nj * 16 + r][((kk * 4 + ql) ^ (r & 7)) * 8];
      }
      short8 af[2][2];
#pragma unroll
      for (int im = 0; im < 2; ++im)
#pragma unroll
        for (int kk = 0; kk < 2; ++kk)
          af[im][kk] = *(const short8*)
              &LA[arow0 + (p * 2 + im) * 16 + r][((kk * 4 + ql) ^ (r & 7)) * 8];
      if (pf) {
        if (p == 0) {
          STG(s2, 0, t + 2);
          STG(s2, 1, t + 2);
        } else {
          STG(s2, 2, t + 2);
        }
      }
      bar_raw();
      __builtin_amdgcn_s_setprio(1);
#pragma unroll
      for (int kk = 0; kk < 2; ++kk)
#pragma unroll
        for (int im = 0; im < 2; ++im)
#pragma unroll
          for (int nj = 0; nj < 4; ++nj)
            acc[p * 2 + im][nj] = __builtin_amdgcn_mfma_f32_16x16x32_bf16(
                af[im][kk], bfr[nj][kk], acc[p * 2 + im][nj], 0, 0, 0);
      __builtin_amdgcn_s_setprio(0);
      if (p == 1) {
        if (pf)
          asm volatile("s_waitcnt vmcnt(6)" ::: "memory");
        else if (t + 1 < NT)
          asm volatile("s_waitcnt vmcnt(0)" ::: "memory");
      }
      __builtin_amdgcn_sched_barrier(0);
      bar_raw();
    }
  }
#undef STG

#pragma unroll
  for (int mi = 0; mi < 4; ++mi) {
#pragma unroll
    for (int nj = 0; nj < 4; ++nj) {
#pragma unroll
      for (int rr = 0; rr < 4; ++rr) {
        int mrow = m0 + wm * 64 + mi * 16 + ql * 4 + rr;
        int ncol = n0 + wn * 64 + nj * 16 + r;
        float val = acc[mi][nj][rr];
        if (ADD_BIAS) val += bias[ncol];
        if (OUT_BF16)
          ((unsigned short*)Cptr)[(size_t)mrow * ldC + ncol] = f2bf(val);
        else
          ((float*)Cptr)[(size_t)mrow * ldC + ncol] = val;
      }
    }
  }
}

// ---------------- prep: G-scan + RoPE + phi + A + V-pack + FUSED kv ----------------
__global__ __launch_bounds__(256)
void k_prep(const unsigned short* __restrict__ qkv, const float* __restrict__ beta,
            unsigned short* __restrict__ Qt, unsigned short* __restrict__ Ag,
            unsigned short* __restrict__ Vg, unsigned short* __restrict__ Mg,
            float* __restrict__ mzg, float* __restrict__ gch) {
  const int ch = blockIdx.x;
  const int bh = blockIdx.y;
  const int b = bh >> 4, h = bh & 15;
  const int tid = threadIdx.x;
  const int t0 = ch * 64;

  __shared__ float Gs[64];
  __shared__ unsigned short Qs[64][132];   // 16.9KB
  __shared__ unsigned short Ks[64][132];   // 16.9KB
  __shared__ unsigned short Vs[128][72];   // 18.4KB  [e][s]
  __shared__ unsigned short Kts[128][72];  // 18.4KB  [d][s]  (total ~71KB -> 2/CU)

  if (tid < 64) {
    float bb = beta[((size_t)(b * 2048 + t0 + tid)) * 16 + h];
#pragma unroll
    for (int off = 1; off < 64; off <<= 1) {
      float o = __shfl_up(bb, off, 64);
      if (tid >= off) bb *= o;
    }
    Gs[tid] = bb;
    if (tid == 63) gch[bh * 32 + ch] = bb;
  }
  __syncthreads();

  const int dgl = tid & 7;
  float invf[8];
#pragma unroll
  for (int j = 0; j < 8; ++j)
    invf[j] = expf((float)(dgl * 8 + j) * -0.14391156831212787f);  // 10000^(-e/64)

  int s = tid >> 3;
#pragma unroll
  for (int rep = 0; rep < 2; ++rep, s += 32) {
    size_t row = ((size_t)(b * 2048 + t0 + s)) * 6144 + (size_t)h * 128;
    short8 qlo = *(const short8*)(qkv + row + dgl * 8);
    short8 qhi = *(const short8*)(qkv + row + 64 + dgl * 8);
    short8 klo = *(const short8*)(qkv + row + 2048 + dgl * 8);
    short8 khi = *(const short8*)(qkv + row + 2048 + 64 + dgl * 8);
    float g = Gs[s];
    float ig = 1.f / g;
    float tg = (float)(t0 + s);
    short8 oql, oqh, okl, okh;
#pragma unroll
    for (int j = 0; j < 8; ++j) {
      float sn, cs;
      __sincosf(tg * invf[j], &sn, &cs);
      float qe = bf2f((unsigned short)qlo[j]), qo = bf2f((unsigned short)qhi[j]);
      float a0 = qe * cs - qo * sn, a1 = qe * sn + qo * cs;
      oql[j] = (short)f2bf(phi_elu1(a0) * g);
      oqh[j] = (short)f2bf(phi_elu1(a1) * g);
      float ke = bf2f((unsigned short)klo[j]), ko = bf2f((unsigned short)khi[j]);
      a0 = ke * cs - ko * sn;
      a1 = ke * sn + ko * cs;
      okl[j] = (short)f2bf(phi_elu1(a0) * ig);
      okh[j] = (short)f2bf(phi_elu1(a1) * ig);
    }
    size_t qbase = (((size_t)bh * 32 + ch) * 64 + s) * 128;
    *(short8*)(Qt + qbase + dgl * 8) = oql;
    *(short8*)(Qt + qbase + 64 + dgl * 8) = oqh;
    *(short8*)&Qs[s][dgl * 8] = oql;
    *(short8*)&Qs[s][64 + dgl * 8] = oqh;
    *(short8*)&Ks[s][dgl * 8] = okl;
    *(short8*)&Ks[s][64 + dgl * 8] = okh;
  }
  // V transpose scatter: thread handles row s2, 32 e-values
  {
    const int s2 = tid >> 2, qe = tid & 3;
    const unsigned short* vrow =
        qkv + ((size_t)(b * 2048 + t0 + s2)) * 6144 + 4096 + (size_t)h * 128 + qe * 32;
#pragma unroll
    for (int i = 0; i < 4; ++i) {
      short8 vv = *(const short8*)(vrow + i * 8);
#pragma unroll
      for (int j = 0; j < 8; ++j) Vs[qe * 32 + i * 8 + j][s2] = (unsigned short)vv[j];
    }
  }
  __syncthreads();

  // Kt pack: thread (d, sh) builds Kt[d][sh*32..+31] -> LDS Kts + mz + Vg out
  {
    const int d = tid >> 1, sh = tid & 1;
    unsigned pk[16];
#pragma unroll
    for (int i = 0; i < 16; ++i)
      pk[i] = (unsigned)Ks[sh * 32 + 2 * i][d] | ((unsigned)Ks[sh * 32 + 2 * i + 1][d] << 16);
#pragma unroll
    for (int i = 0; i < 4; ++i)
      *(uint4*)&Kts[d][sh * 32 + i * 8] = *(uint4*)&pk[i * 4];
    // mz[d] = rowsum_s Kt[d][s] directly from registers
    float zs = 0.f;
#pragma unroll
    for (int i = 0; i < 16; ++i) {
      zs += bf2f((unsigned short)(pk[i] & 0xffffu));
      zs += bf2f((unsigned short)(pk[i] >> 16));
    }
    zs += __shfl_xor(zs, 1, 64);
    if (sh == 0) mzg[((size_t)bh * 32 + ch) * 128 + d] = zs;
    // Vg write: [e][s] packed
    unsigned short* vr = Vg + ((size_t)bh * 32 + ch) * 8192 + (size_t)d * 64 + sh * 32;
#pragma unroll
    for (int i = 0; i < 4; ++i)
      *(uint4*)(vr + i * 8) = *(const uint4*)&Vs[d][sh * 32 + i * 8];
  }

  // intra-chunk A (reads Qs/Ks only)
  {
    const int lane = tid & 63;
    const int w = tid >> 6;
    const int q = lane >> 4, r = lane & 15;
    f32x4 acc[4];
#pragma unroll
    for (int nt = 0; nt < 4; ++nt) acc[nt] = (f32x4){0.f, 0.f, 0.f, 0.f};
#pragma unroll
    for (int kk = 0; kk < 4; ++kk) {
      short8 af = *(const short8*)&Qs[w * 16 + r][kk * 32 + q * 8];
#pragma unroll
      for (int nt = 0; nt < 4; ++nt) {
        short8 bf = *(const short8*)&Ks[nt * 16 + r][kk * 32 + q * 8];
        acc[nt] = __builtin_amdgcn_mfma_f32_16x16x32_bf16(af, bf, acc[nt], 0, 0, 0);
      }
    }
    unsigned short* Agp = Ag + ((size_t)bh * 32 + ch) * 4096;
#pragma unroll
    for (int nt = 0; nt < 4; ++nt) {
#pragma unroll
      for (int rr = 0; rr < 4; ++rr) {
        int t_l = w * 16 + q * 4 + rr;
        int s_l = nt * 16 + r;
        float val = (s_l <= t_l) ? acc[nt][rr] : 0.f;
        Agp[t_l * 64 + s_l] = f2bf(val);
      }
    }
  }

  __syncthreads();  // Kts ready

  // fused k_kv: M[e][d] = sum_s V[e][s] Kt[d][s]
  {
    const int lane = tid & 63;
    const int w = tid >> 6;
    const int q = lane >> 4, r = lane & 15;
    f32x4 acc[2][8];
#pragma unroll
    for (int jj = 0; jj < 2; ++jj)
#pragma unroll
      for (int i = 0; i < 8; ++i) acc[jj][i] = (f32x4){0.f, 0.f, 0.f, 0.f};
#pragma unroll
    for (int kk = 0; kk < 2; ++kk) {
      short8 af[2];
      af[0] = *(const short8*)&Vs[(w * 2 + 0) * 16 + r][kk * 32 + q * 8];
      af[1] = *(const short8*)&Vs[(w * 2 + 1) * 16 + r][kk * 32 + q * 8];
#pragma unroll
      for (int i = 0; i < 8; ++i) {
        short8 bf = *(const short8*)&Kts[i * 16 + r][kk * 32 + q * 8];
        acc[0][i] = __builtin_amdgcn_mfma_f32_16x16x32_bf16(af[0], bf, acc[0][i], 0, 0, 0);
        acc[1][i] = __builtin_amdgcn_mfma_f32_16x16x32_bf16(af[1], bf, acc[1][i], 0, 0, 0);
      }
    }
    unsigned short* Mp = Mg + ((size_t)bh * 32 + ch) * 16384;
#pragma unroll
    for (int jj = 0; jj < 2; ++jj)
#pragma unroll
      for (int i = 0; i < 8; ++i)
#pragma unroll
        for (int rr = 0; rr < 4; ++rr) {
          int e = (w * 2 + jj) * 16 + q * 4 + rr;
          Mp[e * 128 + i * 16 + r] = f2bf(acc[jj][i][rr]);
        }
  }
}

// ---------------- k_sprefix: in-place weighted prefix, 4-deep pipelined -------
__global__ __launch_bounds__(256)
void k_sprefix(unsigned short* __restrict__ Msg, float* __restrict__ mzg,
               const float* __restrict__ gch) {
  const int es = blockIdx.x;
  const int bh = blockIdx.y;
  const int tid = threadIdx.x;
  const int e = es * 16 + (tid >> 4);
  const int d0 = (tid & 15) * 8;
  unsigned short* base = Msg + (size_t)bh * 32 * 16384 + (size_t)e * 128 + d0;
  const float* gp = gch + bh * 32;
  float sv[8];
#pragma unroll
  for (int i = 0; i < 8; ++i) sv[i] = 0.f;
  uint4 mb[2][4];
#pragma unroll
  for (int i = 0; i < 4; ++i) mb[0][i] = *(const uint4*)(base + (size_t)i * 16384);
#pragma unroll
  for (int g = 0; g < 8; ++g) {
    if (g < 7) {
#pragma unroll
      for (int i = 0; i < 4; ++i)
        mb[(g + 1) & 1][i] = *(const uint4*)(base + (size_t)(4 * (g + 1) + i) * 16384);
    }
#pragma unroll
    for (int i = 0; i < 4; ++i) {
      const int c = 4 * g + i;
      uint4 so;
      so.x = (unsigned)f2bf(sv[0]) | ((unsigned)f2bf(sv[1]) << 16);
      so.y = (unsigned)f2bf(sv[2]) | ((unsigned)f2bf(sv[3]) << 16);
      so.z = (unsigned)f2bf(sv[4]) | ((unsigned)f2bf(sv[5]) << 16);
      so.w = (unsigned)f2bf(sv[6]) | ((unsigned)f2bf(sv[7]) << 16);
      *(uint4*)(base + (size_t)c * 16384) = so;
      float gv = gp[c];
      const unsigned short* mp = (const unsigned short*)&mb[g & 1][i];
#pragma unroll
      for (int j = 0; j < 8; ++j) sv[j] = gv * (sv[j] + bf2f(mp[j]));
    }
  }
  // z-prefix (once per bh), same 4-deep grouping
  if (es == 0 && tid < 128) {
    float* zb = mzg + (size_t)bh * 32 * 128 + tid;
    float z = 0.f;
    float zv[2][4];
#pragma unroll
    for (int i = 0; i < 4; ++i) zv[0][i] = zb[(size_t)i * 128];
#pragma unroll
    for (int g = 0; g < 8; ++g) {
      if (g < 7) {
#pragma unroll
        for (int i = 0; i < 4; ++i)
          zv[(g + 1) & 1][i] = zb[(size_t)(4 * (g + 1) + i) * 128];
      }
#pragma unroll
      for (int i = 0; i < 4; ++i) {
        const int c = 4 * g + i;
        zb[(size_t)c * 128] = z;
        z = gp[c] * (z + zv[g & 1][i]);
      }
    }
  }
}

// ---------------- k_out: numer = Q@S + A@V; denom = rowsum(A)+Q.z ----------
__global__ __launch_bounds__(256)
void k_out(const unsigned short* __restrict__ Qt, const unsigned short* __restrict__ Sg,
           const unsigned short* __restrict__ Ag, const unsigned short* __restrict__ Vg,
           const float* __restrict__ zg, unsigned short* __restrict__ numerb) {
  const int ch = blockIdx.x, bh = blockIdx.y;
  const int b = bh >> 4, h = bh & 15;
  const int tid = threadIdx.x, lane = tid & 63, w = tid >> 6;
  const int q = lane >> 4, r = lane & 15;
  __shared__ unsigned short Qs[64][132];   // 16.9KB
  __shared__ unsigned short Ss[128][132];  // 33.8KB [e][d]
  __shared__ unsigned short As[64][72];    //  9.2KB
  __shared__ unsigned short Vs[128][72];   // 18.4KB [e][s]   (total ~79KB -> 2/CU)
  __shared__ float zc[128];
  __shared__ float invs[64];

  const unsigned short* Qg = Qt + ((size_t)bh * 32 + ch) * 8192;
#pragma unroll
  for (int i = 0; i < 4; ++i) {
    int c = tid + i * 256;
    int ss = c >> 4, dg = c & 15;
    *(int4*)&Qs[ss][dg * 8] = *(const int4*)(Qg + ss * 128 + dg * 8);
  }
  const unsigned short* Sp = Sg + ((size_t)bh * 32 + ch) * 16384;
#pragma unroll
  for (int i = 0; i < 8; ++i) {
    int c = tid + i * 256;
    int e = c >> 4, dg = c & 15;
    *(int4*)&Ss[e][dg * 8] = *(const int4*)(Sp + e * 128 + dg * 8);
  }
#pragma unroll
  for (int i = 0; i < 2; ++i) {
    int c = tid + i * 256;
    int t_l = c >> 3, sg = c & 7;
    *(int4*)&As[t_l][sg * 8] =
        *(const int4*)(Ag + ((size_t)bh * 32 + ch) * 4096 + t_l * 64 + sg * 8);
  }
  const unsigned short* Vp = Vg + ((size_t)bh * 32 + ch) * 8192;
#pragma unroll
  for (int i = 0; i < 4; ++i) {
    int c = tid + i * 256;
    int e = c >> 3, sg = c & 7;
    *(int4*)&Vs[e][sg * 8] = *(const int4*)(Vp + e * 64 + sg * 8);
  }
  if (tid < 128) zc[tid] = zg[((size_t)bh * 32 + ch) * 128 + tid];
  __syncthreads();

  f32x4 nacc[8];
#pragma unroll
  for (int j = 0; j < 8; ++j) nacc[j] = (f32x4){0.f, 0.f, 0.f, 0.f};
#pragma unroll
  for (int kk = 0; kk < 4; ++kk) {
    short8 aq = *(const short8*)&Qs[w * 16 + r][kk * 32 + q * 8];
#pragma unroll
    for (int j = 0; j < 8; ++j) {
      short8 bf = *(const short8*)&Ss[j * 16 + r][kk * 32 + q * 8];
      nacc[j] = __builtin_amdgcn_mfma_f32_16x16x32_bf16(aq, bf, nacc[j], 0, 0, 0);
    }
  }
#pragma unroll
  for (int kk = 0; kk < 2; ++kk) {
    short8 aa = *(const short8*)&As[w * 16 + r][kk * 32 + q * 8];
#pragma unroll
    for (int j = 0; j < 8; ++j) {
      short8 bf = *(const short8*)&Vs[j * 16 + r][kk * 32 + q * 8];
      nacc[j] = __builtin_amdgcn_mfma_f32_16x16x32_bf16(aa, bf, nacc[j], 0, 0, 0);
    }
  }
  // denom for row w*16+r  (w in 0..3: 4 waves cover all 64 rows)
  {
    float dsum = 0.f;
#pragma unroll
    for (int kk = 0; kk < 4; ++kk) {
      short8 aq = *(const short8*)&Qs[w * 16 + r][kk * 32 + q * 8];
      const float* zp = &zc[kk * 32 + q * 8];
      float4 z0a = *(const float4*)zp;
      float4 z0b = *(const float4*)(zp + 4);
      dsum = fmaf(bf2f((unsigned short)aq[0]), z0a.x, dsum);
      dsum = fmaf(bf2f((unsigned short)aq[1]), z0a.y, dsum);
      dsum = fmaf(bf2f((unsigned short)aq[2]), z0a.z, dsum);
      dsum = fmaf(bf2f((unsigned short)aq[3]), z0a.w, dsum);
      dsum = fmaf(bf2f((unsigned short)aq[4]), z0b.x, dsum);
      dsum = fmaf(bf2f((unsigned short)aq[5]), z0b.y, dsum);
      dsum = fmaf(bf2f((unsigned short)aq[6]), z0b.z, dsum);
      dsum = fmaf(bf2f((unsigned short)aq[7]), z0b.w, dsum);
    }
#pragma unroll
    for (int kk = 0; kk < 2; ++kk) {
      short8 aa = *(const short8*)&As[w * 16 + r][kk * 32 + q * 8];
#pragma unroll
      for (int j = 0; j < 8; ++j) dsum += bf2f((unsigned short)aa[j]);
    }
    dsum += __shfl_xor(dsum, 16, 64);
    dsum += __shfl_xor(dsum, 32, 64);
    if (lane < 16) invs[w * 16 + lane] = 1.f / (dsum + 1e-6f);
  }
  __syncthreads();
#pragma unroll
  for (int j = 0; j < 8; ++j) {
#pragma unroll
    for (int rr = 0; rr < 4; ++rr) {
      int t_l = w * 16 + q * 4 + rr;
      size_t m = (size_t)b * 2048 + ch * 64 + t_l;
      numerb[m * 2048 + h * 128 + j * 16 + r] = f2bf(nacc[j][rr] * invs[t_l]);
    }
  }
}

extern "C" void kernel_launch(void* const* d_in, const int* in_sizes, int n_in,
                              void* d_out, int out_size, void* d_ws, size_t ws_size,
                              hipStream_t stream) {
  const float* x  = (const float*)d_in[0];
  const float* Wq = (const float*)d_in[1];
  const float* Wk = (const float*)d_in[2];
  const float* Wv = (const float*)d_in[3];
  const float* Wg = (const float*)d_in[4];
  const float* bg = (const float*)d_in[5];
  const float* Wo = (const float*)d_in[6];
  const float* bo = (const float*)d_in[7];

  char* ws = (char*)d_ws;
  unsigned short* xb    = (unsigned short*)(ws);             // 16.8MB; -> Qt
  unsigned short* Qt    = (unsigned short*)(ws);
  unsigned short* Wt    = (unsigned short*)(ws + 16777216);  // 25.2MB; dead after QKV
  float*          mzg   = (float*)(ws + 16777216);           // 0.5MB (prep->sprefix->out)
  float*          gch   = (float*)(ws + 17301504);           // 4KB (prep->sprefix)
  unsigned short* Ag    = (unsigned short*)(ws + 33554432);  // 8.4MB
  unsigned short* Wot   = (unsigned short*)(ws + 41943040);  // 8.4MB
  unsigned short* qkvb  = (unsigned short*)(ws + 50331648);  // 50.3MB; dead after prep
  unsigned short* numerb= (unsigned short*)(ws + 100663296); // 16.8MB
  unsigned short* Vg    = (unsigned short*)(ws + 117440512); // 16.8MB
  float*          beta  = (float*)(ws + 134217728);          // 0.26MB
  unsigned short* Wgt16 = (unsigned short*)(ws + 134479872); // 64KB
  // Mg/Sg bf16 33.5MB lives in d_out (exact fit; overwritten by final GEMM).
  unsigned short* Mg    = (unsigned short*)d_out;

  k_cast<<<8192, 256, 0, stream>>>(x, xb);
  k_transw<<<dim3(32, 32, 5), 256, 0, stream>>>(Wq, Wk, Wv, Wo, Wg, Wt, Wot, Wgt16);
  // QKV GEMM split into two M-halves (~58us each) so mid-pipeline kernels
  // become visible in the top-5 profile.
  k_gemm<true, false><<<dim3(48, 16), 256, 0, stream>>>(
      xb, Wt, qkvb, nullptr, 2048, 6144, 2048, 2048, 6144);
  k_gemm<true, false><<<dim3(48, 16), 256, 0, stream>>>(
      xb + (size_t)2048 * 2048, Wt, qkvb + (size_t)2048 * 6144, nullptr,
      2048, 6144, 2048, 2048, 6144);
  k_betaW<<<1024, 256, 0, stream>>>(xb, Wgt16, bg, beta);
  k_prep<<<dim3(32, 32), 256, 0, stream>>>(qkvb, beta, Qt, Ag, Vg, Mg, mzg, gch);
  k_sprefix<<<dim3(8, 32), 256, 0, stream>>>(Mg, mzg, gch);
  k_out<<<dim3(32, 32), 256, 0, stream>>>(Qt, Mg, Ag, Vg, mzg, numerb);
  k_gemm2<false, true><<<dim3(16, 16), 512, 0, stream>>>(
      numerb, Wot, d_out, bo, 4096, 2048, 2048, 2048, 2048);
}

// Round 12
// 388.468 us; speedup vs baseline: 1.0469x; 1.0388x over previous
//
#include <hip/hip_runtime.h>

// DeltaNet fused pipeline, round 17 (= round 14 base, QKV unsplit again,
// + hybrid k_out: S/V stay in LDS (block-shared — round 15 proved de-LDSing
// them costs 11us), Q/A fragments (per-wave-disjoint rows) go direct
// global->reg. LDS 79->52KB => 3 blocks/CU, one barrier, no invs LDS):
//   k_cast:    x fp32 -> bf16
//   k_transw:  Wq/Wk/Wv -> Wt (N x K bf16), Wo -> Wot, Wg -> Wgt16 (z==4)
//   k_gemm:    bf16 MFMA 128x128 GEMM (QKV), plain mapping (117us)
//   k_betaW:   wave-per-row dot: beta = clip(sigmoid(xb . Wgt16[h] + bg))
//   k_prep:    G-scan + RoPE + phi + intra-chunk A + V-pack + FUSED k_kv
//   k_sprefix: in-place weighted prefix over Mg/mzg, 4-deep pipelined
//   k_out:     hybrid (S/V LDS, Q/A reg, z global, inv via __shfl)
//   k_gemm2:   256x128 triple-buffered GEMM (out-proj), round-12 swizzle
//
// workspace layout (134,742,016 B):
//   0         xb (16.8M) [dead after betaW] -> Qt (prep->out)
//   16777216  Wt (25.2M) [dead after QKV gemm] -> mzg(0.5M)+gch(4K)
//   33554432  Ag (8.4M)  (prep->out)
//   41943040  Wot (8.4M) (transw->final gemm)
//   50331648  qkvb (50.3M) (gemm->prep; dead after)
//   100663296 numerb (16.8M) (out->final gemm)
//   117440512 Vg (16.8M) (prep->out)
//   134217728 beta (0.26M), 134479872 Wgt16 (64K)
//   d_out     Mg/Sg bf16 33.5M (prep->sprefix->out; overwritten by final gemm)

typedef __attribute__((ext_vector_type(8))) short short8;
typedef __attribute__((ext_vector_type(4))) float f32x4;

__device__ __forceinline__ unsigned short f2bf(float f) {
  unsigned u = __float_as_uint(f);
  u += 0x7fffu + ((u >> 16) & 1u);   // RNE
  return (unsigned short)(u >> 16);
}
__device__ __forceinline__ float bf2f(unsigned short s) {
  return __uint_as_float(((unsigned)s) << 16);
}
__device__ __forceinline__ float phi_elu1(float x) {
  return x > 0.f ? x + 1.f : expf(x);
}
__device__ __forceinline__ void gl_lds16(const void* g, void* l) {
  __builtin_amdgcn_global_load_lds(
      (const __attribute__((address_space(1))) void*)g,
      (__attribute__((address_space(3))) void*)l, 16, 0, 0);
}
__device__ __forceinline__ void bar_raw() {
  asm volatile("" ::: "memory");
  __builtin_amdgcn_s_barrier();
  asm volatile("" ::: "memory");
}

// ---------------- cast x -> bf16 ----------------
__global__ __launch_bounds__(256)
void k_cast(const float* __restrict__ x, unsigned short* __restrict__ xb) {
  int i = (blockIdx.x * 256 + threadIdx.x) * 4;
  float4 f = *(const float4*)(x + i);
  uint2 p;
  p.x = (unsigned)f2bf(f.x) | ((unsigned)f2bf(f.y) << 16);
  p.y = (unsigned)f2bf(f.z) | ((unsigned)f2bf(f.w) << 16);
  *(uint2*)(xb + i) = p;
}

// ---------------- transpose+cast weights ----------------
__global__ __launch_bounds__(256)
void k_transw(const float* __restrict__ Wq, const float* __restrict__ Wk,
              const float* __restrict__ Wv, const float* __restrict__ Wo,
              const float* __restrict__ Wg,
              unsigned short* __restrict__ Wt, unsigned short* __restrict__ Wot,
              unsigned short* __restrict__ Wgt16) {
  const int z = blockIdx.z;
  if (z == 4) {
    if (blockIdx.y != 0) return;
    int idx = blockIdx.x * 256 + threadIdx.x;  // 8192 threads
    int h = idx >> 9, k4 = (idx & 511) * 4;
    uint2 p;
    p.x = (unsigned)f2bf(Wg[(k4 + 0) * 16 + h]) | ((unsigned)f2bf(Wg[(k4 + 1) * 16 + h]) << 16);
    p.y = (unsigned)f2bf(Wg[(k4 + 2) * 16 + h]) | ((unsigned)f2bf(Wg[(k4 + 3) * 16 + h]) << 16);
    *(uint2*)(Wgt16 + (size_t)h * 2048 + k4) = p;
    return;
  }
  const float* W = (z == 0) ? Wq : (z == 1) ? Wk : (z == 2) ? Wv : Wo;
  unsigned short* out = (z < 3) ? (Wt + (size_t)z * 2048 * 2048) : Wot;
  __shared__ float tile[64][65];
  const int n0 = blockIdx.x * 64;
  const int k0 = blockIdx.y * 64;
  const int tx = threadIdx.x & 63;
  const int ty = threadIdx.x >> 6;
#pragma unroll
  for (int rl = 0; rl < 16; ++rl) {
    int kk = rl * 4 + ty;
    tile[kk][tx] = W[(size_t)(k0 + kk) * 2048 + n0 + tx];
  }
  __syncthreads();
#pragma unroll
  for (int rl = 0; rl < 16; ++rl) {
    int nn = rl * 4 + ty;
    out[(size_t)(n0 + nn) * 2048 + k0 + tx] = f2bf(tile[tx][nn]);
  }
}

// ---------------- beta ----------------
__global__ __launch_bounds__(256)
void k_betaW(const unsigned short* __restrict__ xb, const unsigned short* __restrict__ Wgt16,
             const float* __restrict__ bg, float* __restrict__ beta) {
  const int w = threadIdx.x >> 6;
  const int lane = threadIdx.x & 63;
  const int m = blockIdx.x * 4 + w;
  const int h = lane & 15, kq = lane >> 4;
  const unsigned short* xr = xb + (size_t)m * 2048 + kq * 512;
  const unsigned short* wr = Wgt16 + (size_t)h * 2048 + kq * 512;
  float acc = 0.f;
#pragma unroll 8
  for (int i = 0; i < 64; ++i) {
    short8 xv = *(const short8*)(xr + i * 8);
    short8 wv = *(const short8*)(wr + i * 8);
#pragma unroll
    for (int j = 0; j < 8; ++j)
      acc = fmaf(bf2f((unsigned short)xv[j]), bf2f((unsigned short)wv[j]), acc);
  }
  acc += __shfl_xor(acc, 16, 64);
  acc += __shfl_xor(acc, 32, 64);
  if (lane < 16) {
    float v = acc + bg[h];
    float bv = 1.f / (1.f + expf(-v));
    beta[(size_t)m * 16 + h] = fminf(fmaxf(bv, 0.8f), 0.9995f);
  }
}

// ---------------- bf16 MFMA GEMM 128x128 (QKV), plain mapping ----------------
template <bool OUT_BF16, bool ADD_BIAS>
__global__ __launch_bounds__(256)
void k_gemm(const unsigned short* __restrict__ A, const unsigned short* __restrict__ Bt,
            void* __restrict__ Cptr, const float* __restrict__ bias,
            int M, int N, int K, int ldA, int ldC) {
  __shared__ __align__(16) unsigned short As[128][64];
  __shared__ __align__(16) unsigned short Bs[128][64];
  const int tid = threadIdx.x;
  const int n0 = blockIdx.x * 128;
  const int m0 = blockIdx.y * 128;
  const int lane = tid & 63;
  const int w = tid >> 6;
  const int wm = w >> 1, wn = w & 1;
  const int q = lane >> 4, r = lane & 15;

  const int srow0 = w * 8 + (lane >> 3);
  const int scol = ((lane & 7) ^ ((lane >> 3) & 7)) * 8;

  f32x4 acc[4][4];
#pragma unroll
  for (int i = 0; i < 4; ++i)
#pragma unroll
    for (int j = 0; j < 4; ++j) acc[i][j] = (f32x4){0.f, 0.f, 0.f, 0.f};

  const unsigned short* A0 = A + (size_t)(m0 + srow0) * ldA + scol;
  const unsigned short* B0 = Bt + (size_t)(n0 + srow0) * K + scol;
  unsigned short* lA = &As[srow0][(lane & 7) * 8];
  unsigned short* lB = &Bs[srow0][(lane & 7) * 8];

  const int rsw = r & 7;

  for (int kt = 0; kt < K; kt += 64) {
    __syncthreads();
#pragma unroll
    for (int i = 0; i < 4; ++i) {
      gl_lds16(A0 + (size_t)i * 32 * ldA + kt, lA + i * 2048);
      gl_lds16(B0 + (size_t)i * 32 * K + kt, lB + i * 2048);
    }
    __syncthreads();
#pragma unroll
    for (int kk = 0; kk < 2; ++kk) {
      const int ps = ((kk * 4 + q) ^ rsw) * 8;
      short8 af[4], bfr[4];
#pragma unroll
      for (int i = 0; i < 4; ++i)
        af[i] = *(const short8*)&As[wm * 64 + i * 16 + r][ps];
#pragma unroll
      for (int j = 0; j < 4; ++j)
        bfr[j] = *(const short8*)&Bs[wn * 64 + j * 16 + r][ps];
#pragma unroll
      for (int i = 0; i < 4; ++i)
#pragma unroll
        for (int j = 0; j < 4; ++j)
          acc[i][j] = __builtin_amdgcn_mfma_f32_16x16x32_bf16(af[i], bfr[j], acc[i][j], 0, 0, 0);
    }
  }
#pragma unroll
  for (int i = 0; i < 4; ++i) {
#pragma unroll
    for (int j = 0; j < 4; ++j) {
#pragma unroll
      for (int rr = 0; rr < 4; ++rr) {
        int mi = m0 + wm * 64 + i * 16 + q * 4 + rr;
        int ni = n0 + wn * 64 + j * 16 + r;
        float val = acc[i][j][rr];
        if (ADD_BIAS) val += bias[ni];
        if (OUT_BF16)
          ((unsigned short*)Cptr)[(size_t)mi * ldC + ni] = f2bf(val);
        else
          ((float*)Cptr)[(size_t)mi * ldC + ni] = val;
      }
    }
  }
}

// ---------------- bf16 MFMA GEMM 256x128, triple-buffered (out-proj) ----------------
template <bool OUT_BF16, bool ADD_BIAS>
__global__ __launch_bounds__(512, 2)
void k_gemm2(const unsigned short* __restrict__ A, const unsigned short* __restrict__ Bt,
             void* __restrict__ Cptr, const float* __restrict__ bias,
             int M, int N, int K, int ldA, int ldC) {
  __shared__ __align__(16) unsigned short Ls[3][3][128][64];  // 144KB
  const int tid = threadIdx.x;
  const int lane = tid & 63;
  const int w = tid >> 6;
  const int wm = w >> 1;
  const int wn = w & 1;
  const int ql = lane >> 4;
  const int r = lane & 15;

  // round-12 swizzle (proven in the 407us pipeline)
  const int nwg = gridDim.x * gridDim.y;
  const int orig = blockIdx.y * gridDim.x + blockIdx.x;
  const int li = (orig & 7) * (nwg >> 3) + (orig >> 3);
  const int m0 = (li & 15) * 256;
  const int n0 = (li >> 4) * 128;

  const int srow = tid >> 3;
  const int sphys = tid & 7;
  const int slog = sphys ^ (srow & 7);
  const unsigned short* Ab = A + (size_t)(m0 + srow) * ldA + slog * 8;
  const unsigned short* Bb = Bt + (size_t)(n0 + srow) * K + slog * 8;

#define STG(st, h, tt)                                                        \
  do {                                                                        \
    const size_t ldx = ((h) == 2) ? (size_t)K : (size_t)ldA;                  \
    const unsigned short* gs =                                                \
        (((h) == 2) ? Bb : (Ab + (size_t)((h) * 128) * ldA)) +                \
        (size_t)(tt) * 64;                                                    \
    unsigned short* ld = &Ls[(st)][(h)][srow][sphys * 8];                     \
    gl_lds16(gs, ld);                                                         \
    gl_lds16(gs + 64 * ldx, ld + 64 * 64);                                    \
  } while (0)

  f32x4 acc[4][4];
#pragma unroll
  for (int i = 0; i < 4; ++i)
#pragma unroll
    for (int j = 0; j < 4; ++j) acc[i][j] = (f32x4){0.f, 0.f, 0.f, 0.f};

  const int NT = K >> 6;

#pragma unroll
  for (int h = 0; h < 3; ++h) STG(0, h, 0);
#pragma unroll
  for (int h = 0; h < 3; ++h) STG(1, h, 1);
  asm volatile("s_waitcnt vmcnt(6)" ::: "memory");
  bar_raw();

  short8 bfr[4][2];

  for (int t = 0; t < NT; ++t) {
    const int st = t % 3;
    const unsigned short (*LA)[64] = Ls[st][wm >> 1];
    const unsigned short (*LB)[64] = Ls[st][2];
    const int arow0 = (wm & 1) * 64;
    const int brow0 = wn * 64;
    const bool pf = (t + 2 < NT);
    const int s2 = (t + 2) % 3;
#pragma unroll
    for (int p = 0; p < 2; ++p) {
      if (p == 0) {
#pragma unroll
        for (int nj = 0; nj < 4; ++nj)
#pragma unroll
          for (int kk = 0; kk < 2; ++kk)
            bfr[nj][kk] = *(const short8*)
                &LB[brow0 + nj * 16 + r][((kk * 4 + ql) ^ (r & 7)) * 8];
      }
      short8 af[2][2];
#pragma unroll
      for (int im = 0; im < 2; ++im)
#pragma unroll
        for (int kk = 0; kk < 2; ++kk)
          af[im][kk] = *(const short8*)
              &LA[arow0 + (p * 2 + im) * 16 + r][((kk * 4 + ql) ^ (r & 7)) * 8];
      if (pf) {
        if (p == 0) {
          STG(s2, 0, t + 2);
          STG(s2, 1, t + 2);
        } else {
          STG(s2, 2, t + 2);
        }
      }
      bar_raw();
      __builtin_amdgcn_s_setprio(1);
#pragma unroll
      for (int kk = 0; kk < 2; ++kk)
#pragma unroll
        for (int im = 0; im < 2; ++im)
#pragma unroll
          for (int nj = 0; nj < 4; ++nj)
            acc[p * 2 + im][nj] = __builtin_amdgcn_mfma_f32_16x16x32_bf16(
                af[im][kk], bfr[nj][kk], acc[p * 2 + im][nj], 0, 0, 0);
      __builtin_amdgcn_s_setprio(0);
      if (p == 1) {
        if (pf)
          asm volatile("s_waitcnt vmcnt(6)" ::: "memory");
        else if (t + 1 < NT)
          asm volatile("s_waitcnt vmcnt(0)" ::: "memory");
      }
      __builtin_amdgcn_sched_barrier(0);
      bar_raw();
    }
  }
#undef STG

#pragma unroll
  for (int mi = 0; mi < 4; ++mi) {
#pragma unroll
    for (int nj = 0; nj < 4; ++nj) {
#pragma unroll
      for (int rr = 0; rr < 4; ++rr) {
        int mrow = m0 + wm * 64 + mi * 16 + ql * 4 + rr;
        int ncol = n0 + wn * 64 + nj * 16 + r;
        float val = acc[mi][nj][rr];
        if (ADD_BIAS) val += bias[ncol];
        if (OUT_BF16)
          ((unsigned short*)Cptr)[(size_t)mrow * ldC + ncol] = f2bf(val);
        else
          ((float*)Cptr)[(size_t)mrow * ldC + ncol] = val;
      }
    }
  }
}

// ---------------- prep: G-scan + RoPE + phi + A + V-pack + FUSED kv ----------------
__global__ __launch_bounds__(256)
void k_prep(const unsigned short* __restrict__ qkv, const float* __restrict__ beta,
            unsigned short* __restrict__ Qt, unsigned short* __restrict__ Ag,
            unsigned short* __restrict__ Vg, unsigned short* __restrict__ Mg,
            float* __restrict__ mzg, float* __restrict__ gch) {
  const int ch = blockIdx.x;
  const int bh = blockIdx.y;
  const int b = bh >> 4, h = bh & 15;
  const int tid = threadIdx.x;
  const int t0 = ch * 64;

  __shared__ float Gs[64];
  __shared__ unsigned short Qs[64][132];   // 16.9KB
  __shared__ unsigned short Ks[64][132];   // 16.9KB
  __shared__ unsigned short Vs[128][72];   // 18.4KB  [e][s]
  __shared__ unsigned short Kts[128][72];  // 18.4KB  [d][s]  (total ~71KB -> 2/CU)

  if (tid < 64) {
    float bb = beta[((size_t)(b * 2048 + t0 + tid)) * 16 + h];
#pragma unroll
    for (int off = 1; off < 64; off <<= 1) {
      float o = __shfl_up(bb, off, 64);
      if (tid >= off) bb *= o;
    }
    Gs[tid] = bb;
    if (tid == 63) gch[bh * 32 + ch] = bb;
  }
  __syncthreads();

  const int dgl = tid & 7;
  float invf[8];
#pragma unroll
  for (int j = 0; j < 8; ++j)
    invf[j] = expf((float)(dgl * 8 + j) * -0.14391156831212787f);  // 10000^(-e/64)

  int s = tid >> 3;
#pragma unroll
  for (int rep = 0; rep < 2; ++rep, s += 32) {
    size_t row = ((size_t)(b * 2048 + t0 + s)) * 6144 + (size_t)h * 128;
    short8 qlo = *(const short8*)(qkv + row + dgl * 8);
    short8 qhi = *(const short8*)(qkv + row + 64 + dgl * 8);
    short8 klo = *(const short8*)(qkv + row + 2048 + dgl * 8);
    short8 khi = *(const short8*)(qkv + row + 2048 + 64 + dgl * 8);
    float g = Gs[s];
    float ig = 1.f / g;
    float tg = (float)(t0 + s);
    short8 oql, oqh, okl, okh;
#pragma unroll
    for (int j = 0; j < 8; ++j) {
      float sn, cs;
      __sincosf(tg * invf[j], &sn, &cs);
      float qe = bf2f((unsigned short)qlo[j]), qo = bf2f((unsigned short)qhi[j]);
      float a0 = qe * cs - qo * sn, a1 = qe * sn + qo * cs;
      oql[j] = (short)f2bf(phi_elu1(a0) * g);
      oqh[j] = (short)f2bf(phi_elu1(a1) * g);
      float ke = bf2f((unsigned short)klo[j]), ko = bf2f((unsigned short)khi[j]);
      a0 = ke * cs - ko * sn;
      a1 = ke * sn + ko * cs;
      okl[j] = (short)f2bf(phi_elu1(a0) * ig);
      okh[j] = (short)f2bf(phi_elu1(a1) * ig);
    }
    size_t qbase = (((size_t)bh * 32 + ch) * 64 + s) * 128;
    *(short8*)(Qt + qbase + dgl * 8) = oql;
    *(short8*)(Qt + qbase + 64 + dgl * 8) = oqh;
    *(short8*)&Qs[s][dgl * 8] = oql;
    *(short8*)&Qs[s][64 + dgl * 8] = oqh;
    *(short8*)&Ks[s][dgl * 8] = okl;
    *(short8*)&Ks[s][64 + dgl * 8] = okh;
  }
  // V transpose scatter: thread handles row s2, 32 e-values
  {
    const int s2 = tid >> 2, qe = tid & 3;
    const unsigned short* vrow =
        qkv + ((size_t)(b * 2048 + t0 + s2)) * 6144 + 4096 + (size_t)h * 128 + qe * 32;
#pragma unroll
    for (int i = 0; i < 4; ++i) {
      short8 vv = *(const short8*)(vrow + i * 8);
#pragma unroll
      for (int j = 0; j < 8; ++j) Vs[qe * 32 + i * 8 + j][s2] = (unsigned short)vv[j];
    }
  }
  __syncthreads();

  // Kt pack: thread (d, sh) builds Kt[d][sh*32..+31] -> LDS Kts + mz + Vg out
  {
    const int d = tid >> 1, sh = tid & 1;
    unsigned pk[16];
#pragma unroll
    for (int i = 0; i < 16; ++i)
      pk[i] = (unsigned)Ks[sh * 32 + 2 * i][d] | ((unsigned)Ks[sh * 32 + 2 * i + 1][d] << 16);
#pragma unroll
    for (int i = 0; i < 4; ++i)
      *(uint4*)&Kts[d][sh * 32 + i * 8] = *(uint4*)&pk[i * 4];
    // mz[d] = rowsum_s Kt[d][s] directly from registers
    float zs = 0.f;
#pragma unroll
    for (int i = 0; i < 16; ++i) {
      zs += bf2f((unsigned short)(pk[i] & 0xffffu));
      zs += bf2f((unsigned short)(pk[i] >> 16));
    }
    zs += __shfl_xor(zs, 1, 64);
    if (sh == 0) mzg[((size_t)bh * 32 + ch) * 128 + d] = zs;
    // Vg write: [e][s] packed
    unsigned short* vr = Vg + ((size_t)bh * 32 + ch) * 8192 + (size_t)d * 64 + sh * 32;
#pragma unroll
    for (int i = 0; i < 4; ++i)
      *(uint4*)(vr + i * 8) = *(const uint4*)&Vs[d][sh * 32 + i * 8];
  }

  // intra-chunk A (reads Qs/Ks only)
  {
    const int lane = tid & 63;
    const int w = tid >> 6;
    const int q = lane >> 4, r = lane & 15;
    f32x4 acc[4];
#pragma unroll
    for (int nt = 0; nt < 4; ++nt) acc[nt] = (f32x4){0.f, 0.f, 0.f, 0.f};
#pragma unroll
    for (int kk = 0; kk < 4; ++kk) {
      short8 af = *(const short8*)&Qs[w * 16 + r][kk * 32 + q * 8];
#pragma unroll
      for (int nt = 0; nt < 4; ++nt) {
        short8 bf = *(const short8*)&Ks[nt * 16 + r][kk * 32 + q * 8];
        acc[nt] = __builtin_amdgcn_mfma_f32_16x16x32_bf16(af, bf, acc[nt], 0, 0, 0);
      }
    }
    unsigned short* Agp = Ag + ((size_t)bh * 32 + ch) * 4096;
#pragma unroll
    for (int nt = 0; nt < 4; ++nt) {
#pragma unroll
      for (int rr = 0; rr < 4; ++rr) {
        int t_l = w * 16 + q * 4 + rr;
        int s_l = nt * 16 + r;
        float val = (s_l <= t_l) ? acc[nt][rr] : 0.f;
        Agp[t_l * 64 + s_l] = f2bf(val);
      }
    }
  }

  __syncthreads();  // Kts ready

  // fused k_kv: M[e][d] = sum_s V[e][s] Kt[d][s]
  {
    const int lane = tid & 63;
    const int w = tid >> 6;
    const int q = lane >> 4, r = lane & 15;
    f32x4 acc[2][8];
#pragma unroll
    for (int jj = 0; jj < 2; ++jj)
#pragma unroll
      for (int i = 0; i < 8; ++i) acc[jj][i] = (f32x4){0.f, 0.f, 0.f, 0.f};
#pragma unroll
    for (int kk = 0; kk < 2; ++kk) {
      short8 af[2];
      af[0] = *(const short8*)&Vs[(w * 2 + 0) * 16 + r][kk * 32 + q * 8];
      af[1] = *(const short8*)&Vs[(w * 2 + 1) * 16 + r][kk * 32 + q * 8];
#pragma unroll
      for (int i = 0; i < 8; ++i) {
        short8 bf = *(const short8*)&Kts[i * 16 + r][kk * 32 + q * 8];
        acc[0][i] = __builtin_amdgcn_mfma_f32_16x16x32_bf16(af[0], bf, acc[0][i], 0, 0, 0);
        acc[1][i] = __builtin_amdgcn_mfma_f32_16x16x32_bf16(af[1], bf, acc[1][i], 0, 0, 0);
      }
    }
    unsigned short* Mp = Mg + ((size_t)bh * 32 + ch) * 16384;
#pragma unroll
    for (int jj = 0; jj < 2; ++jj)
#pragma unroll
      for (int i = 0; i < 8; ++i)
#pragma unroll
        for (int rr = 0; rr < 4; ++rr) {
          int e = (w * 2 + jj) * 16 + q * 4 + rr;
          Mp[e * 128 + i * 16 + r] = f2bf(acc[jj][i][rr]);
        }
  }
}

// ---------------- k_sprefix: in-place weighted prefix, 4-deep pipelined -------
__global__ __launch_bounds__(256)
void k_sprefix(unsigned short* __restrict__ Msg, float* __restrict__ mzg,
               const float* __restrict__ gch) {
  const int es = blockIdx.x;
  const int bh = blockIdx.y;
  const int tid = threadIdx.x;
  const int e = es * 16 + (tid >> 4);
  const int d0 = (tid & 15) * 8;
  unsigned short* base = Msg + (size_t)bh * 32 * 16384 + (size_t)e * 128 + d0;
  const float* gp = gch + bh * 32;
  float sv[8];
#pragma unroll
  for (int i = 0; i < 8; ++i) sv[i] = 0.f;
  uint4 mb[2][4];
#pragma unroll
  for (int i = 0; i < 4; ++i) mb[0][i] = *(const uint4*)(base + (size_t)i * 16384);
#pragma unroll
  for (int g = 0; g < 8; ++g) {
    if (g < 7) {
#pragma unroll
      for (int i = 0; i < 4; ++i)
        mb[(g + 1) & 1][i] = *(const uint4*)(base + (size_t)(4 * (g + 1) + i) * 16384);
    }
#pragma unroll
    for (int i = 0; i < 4; ++i) {
      const int c = 4 * g + i;
      uint4 so;
      so.x = (unsigned)f2bf(sv[0]) | ((unsigned)f2bf(sv[1]) << 16);
      so.y = (unsigned)f2bf(sv[2]) | ((unsigned)f2bf(sv[3]) << 16);
      so.z = (unsigned)f2bf(sv[4]) | ((unsigned)f2bf(sv[5]) << 16);
      so.w = (unsigned)f2bf(sv[6]) | ((unsigned)f2bf(sv[7]) << 16);
      *(uint4*)(base + (size_t)c * 16384) = so;
      float gv = gp[c];
      const unsigned short* mp = (const unsigned short*)&mb[g & 1][i];
#pragma unroll
      for (int j = 0; j < 8; ++j) sv[j] = gv * (sv[j] + bf2f(mp[j]));
    }
  }
  // z-prefix (once per bh), same 4-deep grouping
  if (es == 0 && tid < 128) {
    float* zb = mzg + (size_t)bh * 32 * 128 + tid;
    float z = 0.f;
    float zv[2][4];
#pragma unroll
    for (int i = 0; i < 4; ++i) zv[0][i] = zb[(size_t)i * 128];
#pragma unroll
    for (int g = 0; g < 8; ++g) {
      if (g < 7) {
#pragma unroll
        for (int i = 0; i < 4; ++i)
          zv[(g + 1) & 1][i] = zb[(size_t)(4 * (g + 1) + i) * 128];
      }
#pragma unroll
      for (int i = 0; i < 4; ++i) {
        const int c = 4 * g + i;
        zb[(size_t)c * 128] = z;
        z = gp[c] * (z + zv[g & 1][i]);
      }
    }
  }
}

// ---------------- k_out: hybrid. S/V in LDS (block-shared), Q/A direct to
// regs (per-wave-disjoint rows), z from global (L2-broadcast), inv via
// in-wave __shfl. LDS 52KB -> 3 blocks/CU, single barrier. ----------------
__global__ __launch_bounds__(256)
void k_out(const unsigned short* __restrict__ Qt, const unsigned short* __restrict__ Sg,
           const unsigned short* __restrict__ Ag, const unsigned short* __restrict__ Vg,
           const float* __restrict__ zg, unsigned short* __restrict__ numerb) {
  const int ch = blockIdx.x, bh = blockIdx.y;
  const int b = bh >> 4, h = bh & 15;
  const int tid = threadIdx.x, lane = tid & 63, w = tid >> 6;
  const int q = lane >> 4, r = lane & 15;
  __shared__ unsigned short Ss[128][132];  // 33.8KB [e][d]
  __shared__ unsigned short Vs[128][72];   // 18.4KB [e][s]   (52.2KB -> 3/CU)

  const unsigned short* Sp = Sg + ((size_t)bh * 32 + ch) * 16384;
#pragma unroll
  for (int i = 0; i < 8; ++i) {
    int c = tid + i * 256;
    int e = c >> 4, dg = c & 15;
    *(int4*)&Ss[e][dg * 8] = *(const int4*)(Sp + e * 128 + dg * 8);
  }
  const unsigned short* Vp = Vg + ((size_t)bh * 32 + ch) * 8192;
#pragma unroll
  for (int i = 0; i < 4; ++i) {
    int c = tid + i * 256;
    int e = c >> 3, sg = c & 7;
    *(int4*)&Vs[e][sg * 8] = *(const int4*)(Vp + e * 64 + sg * 8);
  }
  // per-wave-disjoint Q/A rows -> straight to registers (no LDS round-trip)
  const unsigned short* Qg =
      Qt + ((size_t)bh * 32 + ch) * 8192 + (size_t)(w * 16 + r) * 128;
  const unsigned short* Agp =
      Ag + ((size_t)bh * 32 + ch) * 4096 + (size_t)(w * 16 + r) * 64;
  short8 aq[4], aa[2];
#pragma unroll
  for (int kk = 0; kk < 4; ++kk) aq[kk] = *(const short8*)(Qg + kk * 32 + q * 8);
#pragma unroll
  for (int kk = 0; kk < 2; ++kk) aa[kk] = *(const short8*)(Agp + kk * 32 + q * 8);
  const float* zp = zg + ((size_t)bh * 32 + ch) * 128;
  __syncthreads();

  f32x4 nacc[8];
#pragma unroll
  for (int j = 0; j < 8; ++j) nacc[j] = (f32x4){0.f, 0.f, 0.f, 0.f};
#pragma unroll
  for (int kk = 0; kk < 4; ++kk) {
#pragma unroll
    for (int j = 0; j < 8; ++j) {
      short8 bf = *(const short8*)&Ss[j * 16 + r][kk * 32 + q * 8];
      nacc[j] = __builtin_amdgcn_mfma_f32_16x16x32_bf16(aq[kk], bf, nacc[j], 0, 0, 0);
    }
  }
#pragma unroll
  for (int kk = 0; kk < 2; ++kk) {
#pragma unroll
    for (int j = 0; j < 8; ++j) {
      short8 bf = *(const short8*)&Vs[j * 16 + r][kk * 32 + q * 8];
      nacc[j] = __builtin_amdgcn_mfma_f32_16x16x32_bf16(aa[kk], bf, nacc[j], 0, 0, 0);
    }
  }

  // denom for row w*16+r from register frags; z from global (L2 broadcast)
  float dsum = 0.f;
#pragma unroll
  for (int kk = 0; kk < 4; ++kk) {
    float4 z0a = *(const float4*)(zp + kk * 32 + q * 8);
    float4 z0b = *(const float4*)(zp + kk * 32 + q * 8 + 4);
    dsum = fmaf(bf2f((unsigned short)aq[kk][0]), z0a.x, dsum);
    dsum = fmaf(bf2f((unsigned short)aq[kk][1]), z0a.y, dsum);
    dsum = fmaf(bf2f((unsigned short)aq[kk][2]), z0a.z, dsum);
    dsum = fmaf(bf2f((unsigned short)aq[kk][3]), z0a.w, dsum);
    dsum = fmaf(bf2f((unsigned short)aq[kk][4]), z0b.x, dsum);
    dsum = fmaf(bf2f((unsigned short)aq[kk][5]), z0b.y, dsum);
    dsum = fmaf(bf2f((unsigned short)aq[kk][6]), z0b.z, dsum);
    dsum = fmaf(bf2f((unsigned short)aq[kk][7]), z0b.w, dsum);
  }
#pragma unroll
  for (int kk = 0; kk < 2; ++kk)
#pragma unroll
    for (int j = 0; j < 8; ++j) dsum += bf2f((unsigned short)aa[kk][j]);
  dsum += __shfl_xor(dsum, 16, 64);
  dsum += __shfl_xor(dsum, 32, 64);
  const float inv = 1.f / (dsum + 1e-6f);

  // inv for row w*16+(q*4+rr) lives at lane (q*4+rr) of this wave
#pragma unroll
  for (int j = 0; j < 8; ++j) {
#pragma unroll
    for (int rr = 0; rr < 4; ++rr) {
      float inv_r = __shfl(inv, q * 4 + rr, 64);
      int t_l = w * 16 + q * 4 + rr;
      size_t m = (size_t)b * 2048 + ch * 64 + t_l;
      numerb[m * 2048 + h * 128 + j * 16 + r] = f2bf(nacc[j][rr] * inv_r);
    }
  }
}

extern "C" void kernel_launch(void* const* d_in, const int* in_sizes, int n_in,
                              void* d_out, int out_size, void* d_ws, size_t ws_size,
                              hipStream_t stream) {
  const float* x  = (const float*)d_in[0];
  const float* Wq = (const float*)d_in[1];
  const float* Wk = (const float*)d_in[2];
  const float* Wv = (const float*)d_in[3];
  const float* Wg = (const float*)d_in[4];
  const float* bg = (const float*)d_in[5];
  const float* Wo = (const float*)d_in[6];
  const float* bo = (const float*)d_in[7];

  char* ws = (char*)d_ws;
  unsigned short* xb    = (unsigned short*)(ws);             // 16.8MB; -> Qt
  unsigned short* Qt    = (unsigned short*)(ws);
  unsigned short* Wt    = (unsigned short*)(ws + 16777216);  // 25.2MB; dead after QKV
  float*          mzg   = (float*)(ws + 16777216);           // 0.5MB (prep->sprefix->out)
  float*          gch   = (float*)(ws + 17301504);           // 4KB (prep->sprefix)
  unsigned short* Ag    = (unsigned short*)(ws + 33554432);  // 8.4MB
  unsigned short* Wot   = (unsigned short*)(ws + 41943040);  // 8.4MB
  unsigned short* qkvb  = (unsigned short*)(ws + 50331648);  // 50.3MB; dead after prep
  unsigned short* numerb= (unsigned short*)(ws + 100663296); // 16.8MB
  unsigned short* Vg    = (unsigned short*)(ws + 117440512); // 16.8MB
  float*          beta  = (float*)(ws + 134217728);          // 0.26MB
  unsigned short* Wgt16 = (unsigned short*)(ws + 134479872); // 64KB
  // Mg/Sg bf16 33.5MB lives in d_out (exact fit; overwritten by final GEMM).
  unsigned short* Mg    = (unsigned short*)d_out;

  k_cast<<<8192, 256, 0, stream>>>(x, xb);
  k_transw<<<dim3(32, 32, 5), 256, 0, stream>>>(Wq, Wk, Wv, Wo, Wg, Wt, Wot, Wgt16);
  k_gemm<true, false><<<dim3(48, 32), 256, 0, stream>>>(
      xb, Wt, qkvb, nullptr, 4096, 6144, 2048, 2048, 6144);
  k_betaW<<<1024, 256, 0, stream>>>(xb, Wgt16, bg, beta);
  k_prep<<<dim3(32, 32), 256, 0, stream>>>(qkvb, beta, Qt, Ag, Vg, Mg, mzg, gch);
  k_sprefix<<<dim3(8, 32), 256, 0, stream>>>(Mg, mzg, gch);
  k_out<<<dim3(32, 32), 256, 0, stream>>>(Qt, Mg, Ag, Vg, mzg, numerb);
  k_gemm2<false, true><<<dim3(16, 16), 512, 0, stream>>>(
      numerb, Wot, d_out, bo, 4096, 2048, 2048, 2048, 2048);
}